// Round 2
// baseline (1970.641 us; speedup 1.0000x reference)
//
#include <hip/hip_runtime.h>
#include <hip/hip_bf16.h>
#include <math.h>

typedef __hip_bfloat16 bf16;

#define EPSV 1e-5f
#define BNSC 0.99999500003749968f  // 1/sqrt(1+1e-5)

__device__ __forceinline__ float bf2f(bf16 v){ return __bfloat162float(v); }
__device__ __forceinline__ bf16 f2bf(float v){ return __float2bfloat16(v); }

__device__ __forceinline__ float blk_sum(float v, float* sm){
  int tid = threadIdx.x;
  #pragma unroll
  for(int o=32;o>0;o>>=1) v += __shfl_down(v, o, 64);
  if((tid&63)==0) sm[tid>>6] = v;
  __syncthreads();
  float s = 0.f;
  int nw = blockDim.x>>6;
  for(int i=0;i<nw;i++) s += sm[i];
  __syncthreads();
  return s;
}

__device__ __forceinline__ float softplusf(float x){
  return (x > 20.f) ? x : log1pf(expf(x));
}
__device__ __forceinline__ float siluf(float x){
  return x / (1.f + expf(-x));
}

// generic batched transpose: src (Bn,R,C) -> dst (Bn,C,R)
__global__ void transpose_k(const float* __restrict__ src, float* __restrict__ dst,
                            int Bn, int R, int C){
  int idx = blockIdx.x*256 + threadIdx.x;
  int rc = R*C;
  int total = Bn*rc;
  if(idx >= total) return;
  int d = idx / rc;
  int rem = idx - d*rc;
  int i = rem / C;
  int j = rem - i*C;
  dst[d*rc + j*R + i] = src[idx];
}

// R1: per (b,c) slice: col max/min over h (per w), row max/min over w (per h),
// add interpolated pos-emb + argmax index, write PRE-LN into pmax/pmin (b,128,256)
__global__ void r1_reduce_pe(const float* __restrict__ x, const float* __restrict__ pe,
                             float* __restrict__ pmax, float* __restrict__ pmin){
  __shared__ float tile[64*65];
  int bc = blockIdx.x;          // b*256 + c
  int b = bc >> 8, c = bc & 255;
  const float* xp = x + ((size_t)bc << 12);
  for(int i=threadIdx.x; i<4096; i+=64)
    tile[(i>>6)*65 + (i&63)] = xp[i];
  __syncthreads();
  int t = threadIdx.x;          // t = w for cols, t = h for rows  (both N=64)
  float cmx=-3.4e38f, cmn=3.4e38f; int cax=0, can=0;
  for(int h=0;h<64;h++){
    float v = tile[h*65 + t];
    if(v > cmx){ cmx=v; cax=h; }
    if(v < cmn){ cmn=v; can=h; }
  }
  float rmx=-3.4e38f, rmn=3.4e38f; int rax=0, ran=0;
  for(int w=0;w<64;w++){
    float v = tile[t*65 + w];
    if(v > rmx){ rmx=v; rax=w; }
    if(v < rmn){ rmn=v; ran=w; }
  }
  float coords = fmaxf((t + 0.5f)*0.25f - 0.5f, 0.f);
  int i0 = (int)floorf(coords);
  int i1 = min(i0+1, 15);
  float wg = coords - (float)i0;
  float pos = pe[c*16+i0]*(1.f-wg) + pe[c*16+i1]*wg;
  size_t base_col = ((size_t)b*128 + t)*256 + c;
  size_t base_row = ((size_t)b*128 + 64 + t)*256 + c;
  pmax[base_col] = cmx + pos + (float)cax;
  pmin[base_col] = cmn + pos + (float)can;
  pmax[base_row] = rmx + pos + (float)rax;
  pmin[base_row] = rmn + pos + (float)ran;
}

// row LayerNorm over 256, in place
__global__ void ln_rows(float* __restrict__ buf, const float* __restrict__ g,
                        const float* __restrict__ bb){
  __shared__ float sm[8];
  int row = blockIdx.x, t = threadIdx.x;
  float v = buf[(size_t)row*256 + t];
  float m = blk_sum(v, sm) * (1.f/256.f);
  float dv = v - m;
  float var = blk_sum(dv*dv, sm) * (1.f/256.f);
  buf[(size_t)row*256 + t] = dv * rsqrtf(var + EPSV) * g[t] + bb[t];
}

// M1: xz[rb][l][i] = sum_c u(b,l_eff,c) * in_w[d][i][c]   (WTin is [d][c][i])
__global__ void m1_xz(const float* __restrict__ rmax, const float* __restrict__ rmin,
                      const float* __restrict__ WTin, float* __restrict__ xz){
  __shared__ float ut[16*256];
  int bx = blockIdx.x;                 // 256 blocks: r*64 + b*8 + lt
  int r = bx >> 6, rem = bx & 63, b = rem >> 3, lt = rem & 7;
  int d = r & 1;
  const float* u = (r < 2) ? rmax : rmin;
  bool flip = (r & 1);
  for(int i=threadIdx.x; i<16*256; i+=256){
    int lr = i >> 8, c = i & 255;
    int l = lt*16 + lr;
    int le = flip ? (127 - l) : l;
    ut[i] = u[((size_t)b*128 + le)*256 + c];
  }
  __syncthreads();
  const float* W = WTin + (size_t)d*256*1024;
  size_t rowbase = ((size_t)(r*8 + b)*128 + lt*16)*1024;
  for(int j=0;j<4;j++){
    int i = j*256 + threadIdx.x;
    float acc[16];
    #pragma unroll
    for(int q=0;q<16;q++) acc[q] = 0.f;
    for(int c=0;c<256;c++){
      float wv = W[(size_t)c*1024 + i];
      #pragma unroll
      for(int q=0;q<16;q++) acc[q] += wv * ut[(q<<8) + c];
    }
    #pragma unroll
    for(int q=0;q<16;q++) xz[rowbase + (size_t)q*1024 + i] = acc[q];
  }
}

// M2: causal depthwise conv (k=4) + silu over xh part of xz
__global__ void m2_conv(const float* __restrict__ xz, const float* __restrict__ cw,
                        const float* __restrict__ cb, float* __restrict__ xc){
  int idx = blockIdx.x*256 + threadIdx.x;   // < 4*8*128*512
  int dd = idx & 511;
  int l  = (idx >> 9) & 127;
  int rb = idx >> 16;
  int d = (rb >> 3) & 1;
  const float* base = xz + ((size_t)rb*128)*1024 + dd;  // xh[rb][.][dd]
  float s = cb[d*512 + dd];
  const float* w = cw + (size_t)(d*512 + dd)*4;
  #pragma unroll
  for(int k=0;k<4;k++){
    int ls = l - 3 + k;
    if(ls >= 0) s += base[(size_t)ls*1024] * w[k];
  }
  xc[idx] = siluf(s);
}

// M3: dbl[row][e] = sum_dd xc[row][dd] * xproj[d][e][dd]
__global__ void m3_xproj(const float* __restrict__ xc, const float* __restrict__ xproj,
                         float* __restrict__ dbl){
  __shared__ float row[512];
  int rowid = blockIdx.x;          // 4096
  int d = (rowid >> 10) & 1;
  for(int i=threadIdx.x;i<512;i+=64) row[i] = xc[(size_t)rowid*512 + i];
  __syncthreads();
  if(threadIdx.x < 48){
    const float* wp = xproj + (size_t)(d*48 + threadIdx.x)*512;
    float s = 0.f;
    for(int k=0;k<512;k++) s += row[k]*wp[k];
    dbl[(size_t)rowid*48 + threadIdx.x] = s;
  }
}

// M4: dt[row][dd] = softplus(sum_r dbl[row][r]*dt_w[d][dd][r] + dt_b[d][dd])
__global__ void m4_dt(const float* __restrict__ dbl, const float* __restrict__ dtw,
                      const float* __restrict__ dtbias, float* __restrict__ dt){
  int idx = blockIdx.x*256 + threadIdx.x;   // < 2,097,152
  int dd = idx & 511;
  int rowid = idx >> 9;
  int d = (rowid >> 10) & 1;
  const float* dr = dbl + (size_t)rowid*48;
  const float* wp = dtw + (size_t)(d*512 + dd)*16;
  float s = dtbias[d*512 + dd];
  #pragma unroll
  for(int r=0;r<16;r++) s += dr[r]*wp[r];
  dt[idx] = softplusf(s);
}

// M5: selective scan + D-skip + silu(z) gate -> yb
__global__ void m5_scan(const float* __restrict__ dt, const float* __restrict__ xc,
                        const float* __restrict__ dbl, const float* __restrict__ xz,
                        const float* __restrict__ Alog, const float* __restrict__ Dp,
                        float* __restrict__ yb){
  int bx = blockIdx.x;         // 64: r(2b) | b(3b) | half(1b)
  int r = bx >> 4, b = (bx >> 1) & 7, half = bx & 1;
  int dd = half*256 + threadIdx.x;
  int d = r & 1, rb = r*8 + b;
  float A[16], h[16];
  #pragma unroll
  for(int s=0;s<16;s++){
    A[s] = -expf(Alog[(size_t)(d*512 + dd)*16 + s]);
    h[s] = 0.f;
  }
  float Dv = Dp[d*512 + dd];
  for(int l=0;l<128;l++){
    size_t row = (size_t)rb*128 + l;
    float dtv = dt[row*512 + dd];
    float xcv = xc[row*512 + dd];
    float zgv = xz[row*1024 + 512 + dd];
    const float* dr = dbl + row*48;
    float y = 0.f;
    #pragma unroll
    for(int s=0;s<16;s++){
      h[s] = expf(dtv*A[s])*h[s] + dtv*dr[16+s]*xcv;
      y += h[s]*dr[32+s];
    }
    yb[row*512 + dd] = (y + xcv*Dv) * siluf(zgv);
  }
}

// M6: mo[row][o] = sum_dd yb[row][dd] * out_w[d][o][dd]   (WTout is [d][dd][o])
__global__ void m6_outproj(const float* __restrict__ yb, const float* __restrict__ WTout,
                           float* __restrict__ mo){
  __shared__ float yt[16*512];
  int bx = blockIdx.x;          // 256 blocks
  int r = bx >> 6, rem = bx & 63, b = rem >> 3, lt = rem & 7;
  int d = r & 1, rb = r*8 + b;
  size_t rowbase = ((size_t)rb*128 + lt*16);
  for(int i=threadIdx.x;i<16*512;i+=256){
    int lr = i >> 9, dd = i & 511;
    yt[i] = yb[(rowbase + lr)*512 + dd];
  }
  __syncthreads();
  const float* W = WTout + (size_t)d*512*256;
  float acc[16];
  #pragma unroll
  for(int q=0;q<16;q++) acc[q] = 0.f;
  for(int dd=0;dd<512;dd++){
    float wv = W[(size_t)dd*256 + threadIdx.x];
    #pragma unroll
    for(int q=0;q<16;q++) acc[q] += wv * yt[(q<<9) + dd];
  }
  #pragma unroll
  for(int q=0;q<16;q++)
    mo[(rowbase + q)*256 + threadIdx.x] = acc[q];
}

// M7: res_{max,min}[b][l][o] = [fm[b][l][:] , bm[b][127-l][:]] . proj_w[o][:] + proj_b[o]
__global__ void m7_proj(const float* __restrict__ mo, const float* __restrict__ PT,
                        const float* __restrict__ pb, float* __restrict__ resm,
                        float* __restrict__ resn){
  __shared__ float ct[16*512];
  int bx = blockIdx.x;          // 128: t(1b) | b(3b) | lt(3b)
  int t = bx >> 6, rem = bx & 63, b = rem >> 3, lt = rem & 7;
  int fr = t*2, br = t*2 + 1;
  for(int i=threadIdx.x;i<16*512;i+=256){
    int lr = i >> 9, k = i & 511;
    int l = lt*16 + lr;
    ct[i] = (k < 256)
      ? mo[(((size_t)(fr*8+b)*128) + l)*256 + k]
      : mo[(((size_t)(br*8+b)*128) + (127-l))*256 + (k-256)];
  }
  __syncthreads();
  float acc[16];
  #pragma unroll
  for(int q=0;q<16;q++) acc[q] = 0.f;
  for(int k=0;k<512;k++){
    float pv = PT[(size_t)k*256 + threadIdx.x];
    #pragma unroll
    for(int q=0;q<16;q++) acc[q] += pv * ct[(q<<9) + k];
  }
  float* dst = t ? resn : resm;
  float bias = pb[threadIdx.x];
  #pragma unroll
  for(int q=0;q<16;q++)
    dst[((size_t)b*128 + lt*16 + q)*256 + threadIdx.x] = acc[q] + bias;
}

// K1: stride-2 transposed depthwise 3x3 + BN + ReLU -> z1 (bf16, b,c,128,128)
__global__ void k1_deconv(const float* __restrict__ x, const float* __restrict__ wdw,
                          const float* __restrict__ g1, const float* __restrict__ b1,
                          bf16* __restrict__ z1){
  int idx = blockIdx.x*256 + threadIdx.x;   // < 33,554,432
  int w = idx & 127, h = (idx >> 7) & 127, c = (idx >> 14) & 255, b = idx >> 22;
  const float* xp = x + (((size_t)b*256 + c) << 12);
  const float* wp = wdw + c*9;
  int ihA, khA, ihB=0, khB=0, nh;
  if(!(h&1)){ ihA = h>>1; khA = 1; nh = 1; }
  else { ihA = (h-1)>>1; khA = 2; ihB = (h+1)>>1; khB = 0; nh = (ihB < 64) ? 2 : 1; }
  int iwA, kwA, iwB=0, kwB=0, nw_;
  if(!(w&1)){ iwA = w>>1; kwA = 1; nw_ = 1; }
  else { iwA = (w-1)>>1; kwA = 2; iwB = (w+1)>>1; kwB = 0; nw_ = (iwB < 64) ? 2 : 1; }
  float s = xp[ihA*64 + iwA] * wp[khA*3 + kwA];
  if(nw_ == 2) s += xp[ihA*64 + iwB] * wp[khA*3 + kwB];
  if(nh == 2){
    s += xp[ihB*64 + iwA] * wp[khB*3 + kwA];
    if(nw_ == 2) s += xp[ihB*64 + iwB] * wp[khB*3 + kwB];
  }
  s = s * (g1[c]*BNSC) + b1[c];
  z1[idx] = f2bf(fmaxf(s, 0.f));
}

// K2: pointwise 256x256 + BN + clip6 + hard-sigmoid gate -> res (bf16)
__global__ void k2_pw_gate(const bf16* __restrict__ z1, const float* __restrict__ UPT,
                           const float* __restrict__ g2, const float* __restrict__ b2,
                           const float* __restrict__ resm, const float* __restrict__ resn,
                           bf16* __restrict__ res){
  int b = blockIdx.y;
  int p = blockIdx.x*256 + threadIdx.x;   // 16384 pixels / b
  int h = p >> 7, w = p & 127;
  size_t zbase = ((size_t)b*256) << 14;
  const float* rmrow = resm + ((size_t)b*128 + h)*256;
  const float* rnrow = resn + ((size_t)b*128 + w)*256;
  for(int o0=0;o0<256;o0+=32){
    float acc[32];
    #pragma unroll
    for(int j=0;j<32;j++) acc[j] = 0.f;
    for(int c=0;c<256;c++){
      float v = bf2f(z1[zbase + ((size_t)c << 14) + p]);
      const float* wr = UPT + c*256 + o0;
      #pragma unroll
      for(int j=0;j<32;j++) acc[j] += wr[j]*v;
    }
    #pragma unroll
    for(int j=0;j<32;j++){
      int o = o0 + j;
      float zv = acc[j]*(g2[o]*BNSC) + b2[o];
      zv = fminf(fmaxf(zv, 0.f), 6.f);
      float gate = rmrow[o] + rnrow[o] + 3.f;
      gate = fminf(fmaxf(gate, 0.f), 6.f) * (1.f/6.f);
      res[zbase + ((size_t)o << 14) + p] = f2bf(zv * gate);
    }
  }
}

// GN stats: one block per (b,g); src bf16 or f32
__global__ void gn_stats(const void* __restrict__ src, int isbf16, int HW,
                         float* __restrict__ statm, float* __restrict__ statr){
  __shared__ float sm[8];
  int bg = blockIdx.x;           // b*32+g
  int b = bg >> 5, g = bg & 31;
  size_t base = ((size_t)(b*256 + g*8))*(size_t)HW;
  int n = 8*HW;
  float s = 0.f, ss = 0.f;
  if(isbf16){
    const bf16* p = (const bf16*)src + base;
    for(int i=threadIdx.x;i<n;i+=256){ float v = bf2f(p[i]); s += v; ss += v*v; }
  } else {
    const float* p = (const float*)src + base;
    for(int i=threadIdx.x;i<n;i+=256){ float v = p[i]; s += v; ss += v*v; }
  }
  s = blk_sum(s, sm);
  ss = blk_sum(ss, sm);
  if(threadIdx.x == 0){
    float m = s/(float)n;
    float var = ss/(float)n - m*m;
    statm[bg] = m;
    statr[bg] = rsqrtf(var + EPSV);
  }
}

// K4: apply GN1 on the fly, ::2 sample, 256x256 pointwise + BN -> t1 (f32, b,c,64,64)
__global__ void k4_down(const bf16* __restrict__ res, const float* __restrict__ DPT,
                        const float* __restrict__ statm, const float* __restrict__ statr,
                        const float* __restrict__ gng, const float* __restrict__ gnb,
                        const float* __restrict__ dbg, const float* __restrict__ dbb,
                        float* __restrict__ t1){
  __shared__ float sc[256], sb[256];
  int b = blockIdx.y;
  {
    int c = threadIdx.x;
    int g = c >> 3;
    float m = statm[b*32 + g], rs = statr[b*32 + g];
    float s = rs * gng[c];
    sc[c] = s;
    sb[c] = gnb[c] - m*s;
  }
  __syncthreads();
  int p = blockIdx.x*256 + threadIdx.x;    // 4096 pixels / b
  int y = p >> 6, xw = p & 63;
  size_t rbase = ((size_t)b) << 22;
  int soff = y*256 + xw*2;                 // (2y)*128 + 2x
  for(int o0=0;o0<256;o0+=32){
    float acc[32];
    #pragma unroll
    for(int j=0;j<32;j++) acc[j] = 0.f;
    for(int c=0;c<256;c++){
      float v = bf2f(res[rbase + ((size_t)c << 14) + soff]) * sc[c] + sb[c];
      const float* wr = DPT + c*256 + o0;
      #pragma unroll
      for(int j=0;j<32;j++) acc[j] += wr[j]*v;
    }
    #pragma unroll
    for(int j=0;j<32;j++){
      int o = o0 + j;
      t1[(((size_t)b*256 + o) << 12) + p] = acc[j]*(dbg[o]*BNSC) + dbb[o];
    }
  }
}

// K6: t1 = gn2(t1) + x  (in place)
__global__ void k6_gn_add(float* __restrict__ t1, const float* __restrict__ x,
                          const float* __restrict__ statm, const float* __restrict__ statr,
                          const float* __restrict__ gng, const float* __restrict__ gnb){
  int idx = blockIdx.x*256 + threadIdx.x;  // < 8,388,608
  int c = (idx >> 12) & 255, b = idx >> 20, g = c >> 3;
  float m = statm[b*32 + g], rs = statr[b*32 + g];
  t1[idx] = (t1[idx] - m)*rs*gng[c] + gnb[c] + x[idx];
}

// K8: out = gn3(t1)
__global__ void k8_gn_out(const float* __restrict__ t1, const float* __restrict__ statm,
                          const float* __restrict__ statr, const float* __restrict__ gng,
                          const float* __restrict__ gnb, float* __restrict__ out){
  int idx = blockIdx.x*256 + threadIdx.x;
  int c = (idx >> 12) & 255, b = idx >> 20, g = c >> 3;
  float m = statm[b*32 + g], rs = statr[b*32 + g];
  out[idx] = (t1[idx] - m)*rs*gng[c] + gnb[c];
}

extern "C" void kernel_launch(void* const* d_in, const int* in_sizes, int n_in,
                              void* d_out, int out_size, void* d_ws, size_t ws_size,
                              hipStream_t stream){
  const float* x      = (const float*)d_in[0];
  const float* pos    = (const float*)d_in[1];
  const float* ln_g   = (const float*)d_in[2];
  const float* ln_b   = (const float*)d_in[3];
  const float* in_w   = (const float*)d_in[4];
  const float* conv_w = (const float*)d_in[5];
  const float* conv_b = (const float*)d_in[6];
  const float* xproj  = (const float*)d_in[7];
  const float* dt_w   = (const float*)d_in[8];
  const float* dt_b   = (const float*)d_in[9];
  const float* A_log  = (const float*)d_in[10];
  const float* Dp     = (const float*)d_in[11];
  const float* out_w  = (const float*)d_in[12];
  const float* proj_w = (const float*)d_in[13];
  const float* proj_b = (const float*)d_in[14];
  const float* dw_w   = (const float*)d_in[15];
  const float* bn1g   = (const float*)d_in[16];
  const float* bn1b   = (const float*)d_in[17];
  const float* pw_w   = (const float*)d_in[18];
  const float* bn2g   = (const float*)d_in[19];
  const float* bn2b   = (const float*)d_in[20];
  const float* dpw_w  = (const float*)d_in[21];
  const float* dbng   = (const float*)d_in[22];
  const float* dbnb   = (const float*)d_in[23];
  const float* gng    = (const float*)d_in[24];
  const float* gnb    = (const float*)d_in[25];
  float* out = (float*)d_out;

  float* ws = (float*)d_ws;
  // layout (floats); total ~47.4M floats ~= 190 MB
  bf16*  resb = (bf16*)ws;                       // 33,554,432 bf16
  bf16*  z1b  = (bf16*)(ws + 16777216);          // 33,554,432 bf16
  float* zone = ws + 33554432;
  float* xz   = zone;                            // 4,194,304
  float* xc   = xz  + 4194304;                   // 2,097,152
  float* dbl  = xc  + 2097152;                   //   196,608
  float* dtb  = dbl + 196608;                    // 2,097,152
  float* yb   = dtb + 2097152;                   // 2,097,152
  float* t1   = zone;                            // overlay (8,388,608 <= 10,682,368)
  float* mo   = zone + 10682368;                 // 1,048,576
  float* resm = mo   + 1048576;                  //   262,144
  float* resn = resm + 262144;                   //   262,144
  float* pmax = resn + 262144;                   //   262,144
  float* pmin = pmax + 262144;                   //   262,144
  float* WTin = pmin + 262144;                   //   524,288
  float* WTout= WTin + 524288;                   //   262,144
  float* PT   = WTout+ 262144;                   //   131,072
  float* UPT  = PT   + 131072;                   //    65,536
  float* DPT  = UPT  + 65536;                    //    65,536
  float* stat = DPT  + 65536;                    //     1,536

  // weight transposes
  transpose_k<<<(2*1024*256+255)/256,256,0,stream>>>(in_w,  WTin,  2, 1024, 256);
  transpose_k<<<(2*256*512+255)/256, 256,0,stream>>>(out_w, WTout, 2, 256, 512);
  transpose_k<<<(256*512+255)/256,   256,0,stream>>>(proj_w,PT,    1, 256, 512);
  transpose_k<<<(256*256+255)/256,   256,0,stream>>>(pw_w,  UPT,   1, 256, 256);
  transpose_k<<<(256*256+255)/256,   256,0,stream>>>(dpw_w, DPT,   1, 256, 256);

  // reductions + pos-emb + LN -> result_max / result_min (b,128,256)
  r1_reduce_pe<<<2048,64,0,stream>>>(x, pos, pmax, pmin);
  ln_rows<<<1024,256,0,stream>>>(pmax, ln_g, ln_b);   // 8*128 = 1024 rows ONLY
  ln_rows<<<1024,256,0,stream>>>(pmin, ln_g, ln_b);   // (2048 was corrupting WTin)

  // mamba (4 runs batched)
  m1_xz<<<256,256,0,stream>>>(pmax, pmin, WTin, xz);
  m2_conv<<<8192,256,0,stream>>>(xz, conv_w, conv_b, xc);
  m3_xproj<<<4096,64,0,stream>>>(xc, xproj, dbl);
  m4_dt<<<8192,256,0,stream>>>(dbl, dt_w, dt_b, dtb);
  m5_scan<<<64,256,0,stream>>>(dtb, xc, dbl, xz, A_log, Dp, yb);
  m6_outproj<<<256,256,0,stream>>>(yb, WTout, mo);
  ln_rows<<<4096,256,0,stream>>>(mo, ln_g, ln_b);
  m7_proj<<<128,256,0,stream>>>(mo, PT, proj_b, resm, resn);
  ln_rows<<<1024,256,0,stream>>>(resm, ln_g, ln_b);
  ln_rows<<<1024,256,0,stream>>>(resn, ln_g, ln_b);

  // upsample branch
  k1_deconv<<<131072,256,0,stream>>>(x, dw_w, bn1g, bn1b, z1b);
  k2_pw_gate<<<dim3(64,8),256,0,stream>>>(z1b, UPT, bn2g, bn2b, resm, resn, resb);

  // gn1 -> downsample pointwise + bn -> gn2+add x -> gn3 -> out
  gn_stats<<<256,256,0,stream>>>(resb, 1, 16384, stat + 0,    stat + 256);
  k4_down<<<dim3(16,8),256,0,stream>>>(resb, DPT, stat + 0, stat + 256,
                                       gng, gnb, dbng, dbnb, t1);
  gn_stats<<<256,256,0,stream>>>(t1, 0, 4096, stat + 512, stat + 768);
  k6_gn_add<<<32768,256,0,stream>>>(t1, x, stat + 512, stat + 768, gng, gnb);
  gn_stats<<<256,256,0,stream>>>(t1, 0, 4096, stat + 1024, stat + 1280);
  k8_gn_out<<<32768,256,0,stream>>>(t1, stat + 1024, stat + 1280, gng, gnb, out);
}

// Round 3
// 1708.972 us; speedup vs baseline: 1.1531x; 1.1531x over previous
//
#include <hip/hip_runtime.h>
#include <hip/hip_bf16.h>
#include <math.h>

typedef __hip_bfloat16 bf16;
typedef __attribute__((ext_vector_type(8))) short short8_t;
typedef __attribute__((ext_vector_type(4))) short short4_t;
typedef __attribute__((ext_vector_type(4))) float f32x4_t;

#define EPSV 1e-5f
#define BNSC 0.99999500003749968f  // 1/sqrt(1+1e-5)

__device__ __forceinline__ float bf2f(bf16 v){ return __bfloat162float(v); }
__device__ __forceinline__ bf16 f2bf(float v){ return __float2bfloat16(v); }

__device__ __forceinline__ float blk_sum(float v, float* sm){
  int tid = threadIdx.x;
  #pragma unroll
  for(int o=32;o>0;o>>=1) v += __shfl_down(v, o, 64);
  if((tid&63)==0) sm[tid>>6] = v;
  __syncthreads();
  float s = 0.f;
  int nw = blockDim.x>>6;
  for(int i=0;i<nw;i++) s += sm[i];
  __syncthreads();
  return s;
}

__device__ __forceinline__ float softplusf(float x){
  return (x > 20.f) ? x : log1pf(expf(x));
}
__device__ __forceinline__ float siluf(float x){
  return x / (1.f + expf(-x));
}

// generic batched transpose: src (Bn,R,C) -> dst (Bn,C,R)
__global__ void transpose_k(const float* __restrict__ src, float* __restrict__ dst,
                            int Bn, int R, int C){
  int idx = blockIdx.x*256 + threadIdx.x;
  int rc = R*C;
  int total = Bn*rc;
  if(idx >= total) return;
  int d = idx / rc;
  int rem = idx - d*rc;
  int i = rem / C;
  int j = rem - i*C;
  dst[d*rc + j*R + i] = src[idx];
}

// f32 -> bf16 weight convert (keeps [o][c] layout, c contiguous = K-major)
__global__ void wcvt(const float* __restrict__ src, bf16* __restrict__ dst, int n){
  int i = blockIdx.x*256 + threadIdx.x;
  if(i < n) dst[i] = f2bf(src[i]);
}

// R1: per (b,c) slice: col max/min over h, row max/min over w, + pos-emb + idx
__global__ void r1_reduce_pe(const float* __restrict__ x, const float* __restrict__ pe,
                             float* __restrict__ pmax, float* __restrict__ pmin){
  __shared__ float tile[64*65];
  int bc = blockIdx.x;          // b*256 + c
  int b = bc >> 8, c = bc & 255;
  const float* xp = x + ((size_t)bc << 12);
  for(int i=threadIdx.x; i<4096; i+=64)
    tile[(i>>6)*65 + (i&63)] = xp[i];
  __syncthreads();
  int t = threadIdx.x;
  float cmx=-3.4e38f, cmn=3.4e38f; int cax=0, can=0;
  for(int h=0;h<64;h++){
    float v = tile[h*65 + t];
    if(v > cmx){ cmx=v; cax=h; }
    if(v < cmn){ cmn=v; can=h; }
  }
  float rmx=-3.4e38f, rmn=3.4e38f; int rax=0, ran=0;
  for(int w=0;w<64;w++){
    float v = tile[t*65 + w];
    if(v > rmx){ rmx=v; rax=w; }
    if(v < rmn){ rmn=v; ran=w; }
  }
  float coords = fmaxf((t + 0.5f)*0.25f - 0.5f, 0.f);
  int i0 = (int)floorf(coords);
  int i1 = min(i0+1, 15);
  float wg = coords - (float)i0;
  float pos = pe[c*16+i0]*(1.f-wg) + pe[c*16+i1]*wg;
  size_t base_col = ((size_t)b*128 + t)*256 + c;
  size_t base_row = ((size_t)b*128 + 64 + t)*256 + c;
  pmax[base_col] = cmx + pos + (float)cax;
  pmin[base_col] = cmn + pos + (float)can;
  pmax[base_row] = rmx + pos + (float)rax;
  pmin[base_row] = rmn + pos + (float)ran;
}

// row LayerNorm over 256, in place
__global__ void ln_rows(float* __restrict__ buf, const float* __restrict__ g,
                        const float* __restrict__ bb){
  __shared__ float sm[8];
  int row = blockIdx.x, t = threadIdx.x;
  float v = buf[(size_t)row*256 + t];
  float m = blk_sum(v, sm) * (1.f/256.f);
  float dv = v - m;
  float var = blk_sum(dv*dv, sm) * (1.f/256.f);
  buf[(size_t)row*256 + t] = dv * rsqrtf(var + EPSV) * g[t] + bb[t];
}

// M1: xz[rb][l][i] = sum_c u(b,l_eff,c) * in_w[d][i][c]   (WTin is [d][c][i])
__global__ void m1_xz(const float* __restrict__ rmax, const float* __restrict__ rmin,
                      const float* __restrict__ WTin, float* __restrict__ xz){
  __shared__ float ut[16*256];
  int bx = blockIdx.x;                 // 256 blocks: r*64 + b*8 + lt
  int r = bx >> 6, rem = bx & 63, b = rem >> 3, lt = rem & 7;
  int d = r & 1;
  const float* u = (r < 2) ? rmax : rmin;
  bool flip = (r & 1);
  for(int i=threadIdx.x; i<16*256; i+=256){
    int lr = i >> 8, c = i & 255;
    int l = lt*16 + lr;
    int le = flip ? (127 - l) : l;
    ut[i] = u[((size_t)b*128 + le)*256 + c];
  }
  __syncthreads();
  const float* W = WTin + (size_t)d*256*1024;
  size_t rowbase = ((size_t)(r*8 + b)*128 + lt*16)*1024;
  for(int j=0;j<4;j++){
    int i = j*256 + threadIdx.x;
    float acc[16];
    #pragma unroll
    for(int q=0;q<16;q++) acc[q] = 0.f;
    for(int c=0;c<256;c++){
      float wv = W[(size_t)c*1024 + i];
      #pragma unroll
      for(int q=0;q<16;q++) acc[q] += wv * ut[(q<<8) + c];
    }
    #pragma unroll
    for(int q=0;q<16;q++) xz[rowbase + (size_t)q*1024 + i] = acc[q];
  }
}

// M2: causal depthwise conv (k=4) + silu over xh part of xz
__global__ void m2_conv(const float* __restrict__ xz, const float* __restrict__ cw,
                        const float* __restrict__ cb, float* __restrict__ xc){
  int idx = blockIdx.x*256 + threadIdx.x;   // < 4*8*128*512
  int dd = idx & 511;
  int l  = (idx >> 9) & 127;
  int rb = idx >> 16;
  int d = (rb >> 3) & 1;
  const float* base = xz + ((size_t)rb*128)*1024 + dd;  // xh[rb][.][dd]
  float s = cb[d*512 + dd];
  const float* w = cw + (size_t)(d*512 + dd)*4;
  #pragma unroll
  for(int k=0;k<4;k++){
    int ls = l - 3 + k;
    if(ls >= 0) s += base[(size_t)ls*1024] * w[k];
  }
  xc[idx] = siluf(s);
}

// M3: dbl[row][e] = sum_dd xc[row][dd] * xproj[d][e][dd]
__global__ void m3_xproj(const float* __restrict__ xc, const float* __restrict__ xproj,
                         float* __restrict__ dbl){
  __shared__ float row[512];
  int rowid = blockIdx.x;          // 4096
  int d = (rowid >> 10) & 1;
  for(int i=threadIdx.x;i<512;i+=64) row[i] = xc[(size_t)rowid*512 + i];
  __syncthreads();
  if(threadIdx.x < 48){
    const float* wp = xproj + (size_t)(d*48 + threadIdx.x)*512;
    float s = 0.f;
    for(int k=0;k<512;k++) s += row[k]*wp[k];
    dbl[(size_t)rowid*48 + threadIdx.x] = s;
  }
}

// M4: dt[row][dd] = softplus(sum_r dbl[row][r]*dt_w[d][dd][r] + dt_b[d][dd])
__global__ void m4_dt(const float* __restrict__ dbl, const float* __restrict__ dtw,
                      const float* __restrict__ dtbias, float* __restrict__ dt){
  int idx = blockIdx.x*256 + threadIdx.x;   // < 2,097,152
  int dd = idx & 511;
  int rowid = idx >> 9;
  int d = (rowid >> 10) & 1;
  const float* dr = dbl + (size_t)rowid*48;
  const float* wp = dtw + (size_t)(d*512 + dd)*16;
  float s = dtbias[d*512 + dd];
  #pragma unroll
  for(int r=0;r<16;r++) s += dr[r]*wp[r];
  dt[idx] = softplusf(s);
}

// M5: selective scan + D-skip + silu(z) gate -> yb
__global__ void m5_scan(const float* __restrict__ dt, const float* __restrict__ xc,
                        const float* __restrict__ dbl, const float* __restrict__ xz,
                        const float* __restrict__ Alog, const float* __restrict__ Dp,
                        float* __restrict__ yb){
  int bx = blockIdx.x;         // 64: r(2b) | b(3b) | half(1b)
  int r = bx >> 4, b = (bx >> 1) & 7, half = bx & 1;
  int dd = half*256 + threadIdx.x;
  int d = r & 1, rb = r*8 + b;
  float A[16], h[16];
  #pragma unroll
  for(int s=0;s<16;s++){
    A[s] = -expf(Alog[(size_t)(d*512 + dd)*16 + s]);
    h[s] = 0.f;
  }
  float Dv = Dp[d*512 + dd];
  for(int l=0;l<128;l++){
    size_t row = (size_t)rb*128 + l;
    float dtv = dt[row*512 + dd];
    float xcv = xc[row*512 + dd];
    float zgv = xz[row*1024 + 512 + dd];
    const float* dr = dbl + row*48;
    float y = 0.f;
    #pragma unroll
    for(int s=0;s<16;s++){
      h[s] = expf(dtv*A[s])*h[s] + dtv*dr[16+s]*xcv;
      y += h[s]*dr[32+s];
    }
    yb[row*512 + dd] = (y + xcv*Dv) * siluf(zgv);
  }
}

// M6: mo[row][o] = sum_dd yb[row][dd] * out_w[d][o][dd]   (WTout is [d][dd][o])
__global__ void m6_outproj(const float* __restrict__ yb, const float* __restrict__ WTout,
                           float* __restrict__ mo){
  __shared__ float yt[16*512];
  int bx = blockIdx.x;          // 256 blocks
  int r = bx >> 6, rem = bx & 63, b = rem >> 3, lt = rem & 7;
  int d = r & 1, rb = r*8 + b;
  size_t rowbase = ((size_t)rb*128 + lt*16);
  for(int i=threadIdx.x;i<16*512;i+=256){
    int lr = i >> 9, dd = i & 511;
    yt[i] = yb[(rowbase + lr)*512 + dd];
  }
  __syncthreads();
  const float* W = WTout + (size_t)d*512*256;
  float acc[16];
  #pragma unroll
  for(int q=0;q<16;q++) acc[q] = 0.f;
  for(int dd=0;dd<512;dd++){
    float wv = W[(size_t)dd*256 + threadIdx.x];
    #pragma unroll
    for(int q=0;q<16;q++) acc[q] += wv * yt[(q<<9) + dd];
  }
  #pragma unroll
  for(int q=0;q<16;q++)
    mo[(rowbase + q)*256 + threadIdx.x] = acc[q];
}

// M7: res_{max,min}[b][l][o] = [fm[b][l][:] , bm[b][127-l][:]] . proj_w[o][:] + proj_b[o]
__global__ void m7_proj(const float* __restrict__ mo, const float* __restrict__ PT,
                        const float* __restrict__ pb, float* __restrict__ resm,
                        float* __restrict__ resn){
  __shared__ float ct[16*512];
  int bx = blockIdx.x;          // 128: t(1b) | b(3b) | lt(3b)
  int t = bx >> 6, rem = bx & 63, b = rem >> 3, lt = rem & 7;
  int fr = t*2, br = t*2 + 1;
  for(int i=threadIdx.x;i<16*512;i+=256){
    int lr = i >> 9, k = i & 511;
    int l = lt*16 + lr;
    ct[i] = (k < 256)
      ? mo[(((size_t)(fr*8+b)*128) + l)*256 + k]
      : mo[(((size_t)(br*8+b)*128) + (127-l))*256 + (k-256)];
  }
  __syncthreads();
  float acc[16];
  #pragma unroll
  for(int q=0;q<16;q++) acc[q] = 0.f;
  for(int k=0;k<512;k++){
    float pv = PT[(size_t)k*256 + threadIdx.x];
    #pragma unroll
    for(int q=0;q<16;q++) acc[q] += pv * ct[(q<<9) + k];
  }
  float* dst = t ? resn : resm;
  float bias = pb[threadIdx.x];
  #pragma unroll
  for(int q=0;q<16;q++)
    dst[((size_t)b*128 + lt*16 + q)*256 + threadIdx.x] = acc[q] + bias;
}

// K1: stride-2 transposed depthwise 3x3 + BN + ReLU -> zT (bf16, [b][p][c] pixel-major)
// block: (b, h, w-half). 256 threads = channel. LDS transpose tile 64w x 264c.
__global__ void k1_deconv_T(const float* __restrict__ x, const float* __restrict__ wdw,
                            const float* __restrict__ g1, const float* __restrict__ b1,
                            bf16* __restrict__ zT){
  __shared__ bf16 tile[64*264];
  int bx = blockIdx.x;                 // b*256 + h*2 + half
  int b = bx >> 8, rem = bx & 255, h = rem >> 1, half = rem & 1;
  int w0 = half*64;
  int c = threadIdx.x;
  const float* xp = x + (((size_t)b*256 + c) << 12);
  const float* wp = wdw + c*9;
  float scale = g1[c]*BNSC, bias = b1[c];
  int h_even = !(h&1);
  int ihA = h_even ? (h>>1) : ((h-1)>>1);
  int ihB = (h+1)>>1;
  int khA = h_even ? 1 : 2;
  bool hasB = (!h_even) && (ihB < 64);
  const float* rA = xp + ihA*64;
  const float* rB = xp + ihB*64;
  for(int wi=0; wi<64; wi++){
    int w = w0 + wi;
    int w_even = !(w&1);
    int iwA = w_even ? (w>>1) : ((w-1)>>1);
    int iwB = (w+1)>>1;
    int kwA = w_even ? 1 : 2;
    bool wB = (!w_even) && (iwB < 64);
    float s = rA[iwA]*wp[khA*3+kwA];
    if(wB) s += rA[iwB]*wp[khA*3];         // kw=0
    if(hasB){
      s += rB[iwA]*wp[kwA];                // kh=0
      if(wB) s += rB[iwB]*wp[0];
    }
    s = fmaxf(s*scale + bias, 0.f);
    tile[wi*264 + c] = f2bf(s);
  }
  __syncthreads();
  // write out 64 rows x 256 c, coalesced
  int cc = (threadIdx.x & 31)*8;
  size_t obase = (((size_t)b*16384) + (size_t)h*128 + w0)*256;
  for(int i = threadIdx.x>>5; i<64; i+=8){
    short8_t v = *(const short8_t*)&tile[i*264 + cc];
    *(short8_t*)((short*)zT + obase + (size_t)i*256 + cc) = v;
  }
}

// K2 (MFMA): resT[b][p][o] = hsig_gate * clip6(BN(sum_c W[o][c]*zT[b][p][c]))
// block tile: O=256 (m) x P=64 (n), K=256. 4 waves, wave w: o in [64w,64w+64)
__global__ __launch_bounds__(256,2)
void k2_mfma(const bf16* __restrict__ zT, const bf16* __restrict__ Wub,
             const float* __restrict__ g2, const float* __restrict__ b2,
             const float* __restrict__ resm, const float* __restrict__ resn,
             bf16* __restrict__ resT){
  __shared__ bf16 zt[64*264];
  int b = blockIdx.y;
  int p0 = blockIdx.x*64;
  int t = threadIdx.x;
  {
    const short* src = (const short*)zT + (((size_t)b*16384 + p0)*256);
    int pr = t>>5;
    int cc = (t&31)*8;
    #pragma unroll
    for(int i=0;i<8;i++){
      int p = pr + i*8;
      short8_t v = *(const short8_t*)(src + (size_t)p*256 + cc);
      *(short8_t*)&zt[p*264 + cc] = v;
    }
  }
  __syncthreads();
  int wv = t>>6, lane = t&63, quad = lane>>4, l16 = lane&15;
  int m0 = wv*64;
  f32x4_t acc[4][4];
  #pragma unroll
  for(int ms=0;ms<4;ms++)
    #pragma unroll
    for(int ns=0;ns<4;ns++) acc[ms][ns] = (f32x4_t){0.f,0.f,0.f,0.f};
  for(int k0=0;k0<256;k0+=32){
    short8_t afr[4], bfr[4];
    const short* wp = (const short*)Wub + (size_t)(m0 + l16)*256 + k0 + quad*8;
    #pragma unroll
    for(int ms=0;ms<4;ms++) afr[ms] = *(const short8_t*)(wp + (size_t)ms*16*256);
    #pragma unroll
    for(int ns=0;ns<4;ns++) bfr[ns] = *(const short8_t*)&zt[(ns*16 + l16)*264 + k0 + quad*8];
    #pragma unroll
    for(int ms=0;ms<4;ms++)
      #pragma unroll
      for(int ns=0;ns<4;ns++)
        acc[ms][ns] = __builtin_amdgcn_mfma_f32_16x16x32_bf16(afr[ms], bfr[ns], acc[ms][ns], 0,0,0);
  }
  // D[o][p]: lane: p = p0+ns*16+l16 (fixed), o = m0+ms*16+quad*4+r
  #pragma unroll
  for(int ns=0;ns<4;ns++){
    int p = p0 + ns*16 + l16;
    int hh = p>>7, ww = p&127;
    const float* rm = resm + ((size_t)b*128+hh)*256;
    const float* rn = resn + ((size_t)b*128+ww)*256;
    size_t orow = ((size_t)b*16384 + p)*256;
    #pragma unroll
    for(int ms=0;ms<4;ms++){
      int o = m0 + ms*16 + quad*4;
      f32x4_t a = acc[ms][ns];
      f32x4_t gv = *(const f32x4_t*)(g2+o);
      f32x4_t bv = *(const f32x4_t*)(b2+o);
      f32x4_t rmv = *(const f32x4_t*)(rm+o);
      f32x4_t rnv = *(const f32x4_t*)(rn+o);
      alignas(8) bf16 ov[4];
      #pragma unroll
      for(int r=0;r<4;r++){
        float zv = a[r]*(gv[r]*BNSC) + bv[r];
        zv = fminf(fmaxf(zv, 0.f), 6.f);
        float gate = fminf(fmaxf(rmv[r]+rnv[r]+3.f, 0.f), 6.f)*(1.f/6.f);
        ov[r] = f2bf(zv*gate);
      }
      *(short4_t*)((short*)resT + orow + o) = *(const short4_t*)ov;
    }
  }
}

// zero the gn1 accumulators
__global__ void gn_zero(float* __restrict__ p, int n){
  int i = blockIdx.x*256 + threadIdx.x;
  if(i<n) p[i] = 0.f;
}

// GN1 stats over pixel-major resT: per (b, p-chunk of 256): per-channel partials -> group atomics
__global__ void gn_stats_pm(const bf16* __restrict__ resT, float* __restrict__ sum,
                            float* __restrict__ ssq){
  __shared__ float ls[256], lq[256];
  int b = blockIdx.y, p0 = blockIdx.x*256;
  int c = threadIdx.x;
  const short* src = (const short*)resT + ((size_t)b*16384 + p0)*256 + c;
  float s=0.f, q=0.f;
  for(int i=0;i<256;i++){
    bf16 raw; *(short*)&raw = src[(size_t)i*256];
    float v = bf2f(raw);
    s += v; q += v*v;
  }
  ls[c]=s; lq[c]=q;
  __syncthreads();
  if(c<32){
    float S=0.f,Q=0.f;
    #pragma unroll
    for(int j=0;j<8;j++){ S+=ls[c*8+j]; Q+=lq[c*8+j]; }
    atomicAdd(&sum[b*32+c], S);
    atomicAdd(&ssq[b*32+c], Q);
  }
}

__global__ void gn_fin(const float* __restrict__ sum, const float* __restrict__ ssq,
                       float* __restrict__ statm, float* __restrict__ statr){
  int i = threadIdx.x;  // 256 = 8b*32g
  float m = sum[i] * (1.f/131072.f);
  float var = ssq[i] * (1.f/131072.f) - m*m;
  statm[i] = m;
  statr[i] = rsqrtf(var + EPSV);
}

// K4 (MFMA): t1[b][o][p'] = BN(sum_c Wd[o][c] * gn1(resT[b][2y,2x][c]))
// block tile: P=64 sampled pixels (m) x O=256 (n), K=256
__global__ __launch_bounds__(256,2)
void k4_mfma(const bf16* __restrict__ resT, const bf16* __restrict__ Wdb,
             const float* __restrict__ statm, const float* __restrict__ statr,
             const float* __restrict__ gng, const float* __restrict__ gnb,
             const float* __restrict__ dbg, const float* __restrict__ dbb,
             float* __restrict__ t1){
  __shared__ bf16 at[64*264];
  __shared__ float sc[256], sb[256];
  int b = blockIdx.y;
  int q0 = blockIdx.x*64;
  int t = threadIdx.x;
  {
    int cch = t, g = cch>>3;
    float m = statm[b*32+g], rs = statr[b*32+g];
    float s = rs*gng[cch];
    sc[cch] = s; sb[cch] = gnb[cch] - m*s;
  }
  __syncthreads();
  {
    int pr = t>>5;
    int cc = (t&31)*8;
    #pragma unroll
    for(int i=0;i<8;i++){
      int q = pr + i*8;
      int qq = q0 + q;
      int y = qq>>6, xw = qq&63;
      size_t srow = ((size_t)b*16384 + (size_t)y*256 + xw*2)*256;
      short8_t v = *(const short8_t*)((const short*)resT + srow + cc);
      const bf16* vv = (const bf16*)&v;
      alignas(16) bf16 ov[8];
      #pragma unroll
      for(int j=0;j<8;j++) ov[j] = f2bf(bf2f(vv[j])*sc[cc+j] + sb[cc+j]);
      *(short8_t*)&at[q*264 + cc] = *(const short8_t*)ov;
    }
  }
  __syncthreads();
  int wv = t>>6, lane = t&63, quad = lane>>4, l16 = lane&15;
  int n0 = wv*64;
  f32x4_t acc[4][4];
  #pragma unroll
  for(int ms=0;ms<4;ms++)
    #pragma unroll
    for(int ns=0;ns<4;ns++) acc[ms][ns] = (f32x4_t){0.f,0.f,0.f,0.f};
  for(int k0=0;k0<256;k0+=32){
    short8_t afr[4], bfr[4];
    #pragma unroll
    for(int ms=0;ms<4;ms++) afr[ms] = *(const short8_t*)&at[(ms*16 + l16)*264 + k0 + quad*8];
    const short* wp = (const short*)Wdb + (size_t)(n0 + l16)*256 + k0 + quad*8;
    #pragma unroll
    for(int ns=0;ns<4;ns++) bfr[ns] = *(const short8_t*)(wp + (size_t)ns*16*256);
    #pragma unroll
    for(int ms=0;ms<4;ms++)
      #pragma unroll
      for(int ns=0;ns<4;ns++)
        acc[ms][ns] = __builtin_amdgcn_mfma_f32_16x16x32_bf16(afr[ms], bfr[ns], acc[ms][ns], 0,0,0);
  }
  // D[p][o]: lane: o = n0+ns*16+l16 (fixed), p = q0+ms*16+quad*4+r
  #pragma unroll
  for(int ns=0;ns<4;ns++){
    int o = n0 + ns*16 + l16;
    float s2 = dbg[o]*BNSC, bb2 = dbb[o];
    float* dst = t1 + (((size_t)b*256 + o) << 12);
    #pragma unroll
    for(int ms=0;ms<4;ms++){
      int ps = q0 + ms*16 + quad*4;
      f32x4_t a = acc[ms][ns];
      f32x4_t ov;
      #pragma unroll
      for(int r=0;r<4;r++) ov[r] = a[r]*s2 + bb2;
      *(f32x4_t*)(dst + ps) = ov;
    }
  }
}

// GN stats over channel-major f32 (t1): one block per (b,g)
__global__ void gn_stats(const float* __restrict__ src, int HW,
                         float* __restrict__ statm, float* __restrict__ statr){
  __shared__ float sm[8];
  int bg = blockIdx.x;
  int b = bg >> 5, g = bg & 31;
  size_t base = ((size_t)(b*256 + g*8))*(size_t)HW;
  int n = 8*HW;
  const float* p = src + base;
  float s = 0.f, ss = 0.f;
  for(int i=threadIdx.x;i<n;i+=256){ float v = p[i]; s += v; ss += v*v; }
  s = blk_sum(s, sm);
  ss = blk_sum(ss, sm);
  if(threadIdx.x == 0){
    float m = s/(float)n;
    float var = ss/(float)n - m*m;
    statm[bg] = m;
    statr[bg] = rsqrtf(var + EPSV);
  }
}

// K6: t1 = gn2(t1) + x  (in place)
__global__ void k6_gn_add(float* __restrict__ t1, const float* __restrict__ x,
                          const float* __restrict__ statm, const float* __restrict__ statr,
                          const float* __restrict__ gng, const float* __restrict__ gnb){
  int idx = blockIdx.x*256 + threadIdx.x;
  int c = (idx >> 12) & 255, b = idx >> 20, g = c >> 3;
  float m = statm[b*32 + g], rs = statr[b*32 + g];
  t1[idx] = (t1[idx] - m)*rs*gng[c] + gnb[c] + x[idx];
}

// K8: out = gn3(t1)
__global__ void k8_gn_out(const float* __restrict__ t1, const float* __restrict__ statm,
                          const float* __restrict__ statr, const float* __restrict__ gng,
                          const float* __restrict__ gnb, float* __restrict__ out){
  int idx = blockIdx.x*256 + threadIdx.x;
  int c = (idx >> 12) & 255, b = idx >> 20, g = c >> 3;
  float m = statm[b*32 + g], rs = statr[b*32 + g];
  out[idx] = (t1[idx] - m)*rs*gng[c] + gnb[c];
}

extern "C" void kernel_launch(void* const* d_in, const int* in_sizes, int n_in,
                              void* d_out, int out_size, void* d_ws, size_t ws_size,
                              hipStream_t stream){
  const float* x      = (const float*)d_in[0];
  const float* pos    = (const float*)d_in[1];
  const float* ln_g   = (const float*)d_in[2];
  const float* ln_b   = (const float*)d_in[3];
  const float* in_w   = (const float*)d_in[4];
  const float* conv_w = (const float*)d_in[5];
  const float* conv_b = (const float*)d_in[6];
  const float* xproj  = (const float*)d_in[7];
  const float* dt_w   = (const float*)d_in[8];
  const float* dt_b   = (const float*)d_in[9];
  const float* A_log  = (const float*)d_in[10];
  const float* Dp     = (const float*)d_in[11];
  const float* out_w  = (const float*)d_in[12];
  const float* proj_w = (const float*)d_in[13];
  const float* proj_b = (const float*)d_in[14];
  const float* dw_w   = (const float*)d_in[15];
  const float* bn1g   = (const float*)d_in[16];
  const float* bn1b   = (const float*)d_in[17];
  const float* pw_w   = (const float*)d_in[18];
  const float* bn2g   = (const float*)d_in[19];
  const float* bn2b   = (const float*)d_in[20];
  const float* dpw_w  = (const float*)d_in[21];
  const float* dbng   = (const float*)d_in[22];
  const float* dbnb   = (const float*)d_in[23];
  const float* gng    = (const float*)d_in[24];
  const float* gnb    = (const float*)d_in[25];
  float* out = (float*)d_out;

  float* ws = (float*)d_ws;
  bf16*  resT = (bf16*)ws;                       // 33,554,432 bf16 (pixel-major)
  bf16*  zT   = (bf16*)(ws + 16777216);          // 33,554,432 bf16 (pixel-major)
  float* zone = ws + 33554432;
  float* xz   = zone;                            // 4,194,304
  float* xc   = xz  + 4194304;                   // 2,097,152
  float* dbl  = xc  + 2097152;                   //   196,608
  float* dtb  = dbl + 196608;                    // 2,097,152
  float* yb   = dtb + 2097152;                   // 2,097,152
  float* t1   = zone;                            // overlay (8,388,608 <= 10,682,368)
  float* mo   = zone + 10682368;                 // 1,048,576
  float* resm = mo   + 1048576;                  //   262,144
  float* resn = resm + 262144;                   //   262,144
  float* pmax = resn + 262144;                   //   262,144
  float* pmin = pmax + 262144;                   //   262,144
  float* WTin = pmin + 262144;                   //   524,288
  float* WTout= WTin + 524288;                   //   262,144
  float* PT   = WTout+ 262144;                   //   131,072
  bf16*  Wub  = (bf16*)(PT + 131072);            //    65,536 bf16 (32,768 f)
  bf16*  Wdb  = (bf16*)(PT + 131072 + 32768);    //    65,536 bf16 (32,768 f)
  float* stat = PT + 131072 + 65536;             //     2,048
  float* statm1 = stat;        float* statr1 = stat + 256;
  float* statm2 = stat + 512;  float* statr2 = stat + 768;
  float* statm3 = stat + 1024; float* statr3 = stat + 1280;
  float* gsum   = stat + 1536; float* gssq   = stat + 1792;

  // weight prep
  transpose_k<<<(2*1024*256+255)/256,256,0,stream>>>(in_w,  WTin,  2, 1024, 256);
  transpose_k<<<(2*256*512+255)/256, 256,0,stream>>>(out_w, WTout, 2, 256, 512);
  transpose_k<<<(256*512+255)/256,   256,0,stream>>>(proj_w,PT,    1, 256, 512);
  wcvt<<<256,256,0,stream>>>(pw_w,  Wub, 65536);
  wcvt<<<256,256,0,stream>>>(dpw_w, Wdb, 65536);

  // reductions + pos-emb + LN -> result_max / result_min (b,128,256)
  r1_reduce_pe<<<2048,64,0,stream>>>(x, pos, pmax, pmin);
  ln_rows<<<1024,256,0,stream>>>(pmax, ln_g, ln_b);
  ln_rows<<<1024,256,0,stream>>>(pmin, ln_g, ln_b);

  // mamba (4 runs batched)
  m1_xz<<<256,256,0,stream>>>(pmax, pmin, WTin, xz);
  m2_conv<<<8192,256,0,stream>>>(xz, conv_w, conv_b, xc);
  m3_xproj<<<4096,64,0,stream>>>(xc, xproj, dbl);
  m4_dt<<<8192,256,0,stream>>>(dbl, dt_w, dt_b, dtb);
  m5_scan<<<64,256,0,stream>>>(dtb, xc, dbl, xz, A_log, Dp, yb);
  m6_outproj<<<256,256,0,stream>>>(yb, WTout, mo);
  ln_rows<<<4096,256,0,stream>>>(mo, ln_g, ln_b);
  m7_proj<<<128,256,0,stream>>>(mo, PT, proj_b, resm, resn);
  ln_rows<<<1024,256,0,stream>>>(resm, ln_g, ln_b);
  ln_rows<<<1024,256,0,stream>>>(resn, ln_g, ln_b);

  // upsample branch (pixel-major) + MFMA pointwise + gate
  k1_deconv_T<<<2048,256,0,stream>>>(x, dw_w, bn1g, bn1b, zT);
  k2_mfma<<<dim3(256,8),256,0,stream>>>(zT, Wub, bn2g, bn2b, resm, resn, resT);

  // gn1 stats (pixel-major) -> MFMA downsample pointwise + BN
  gn_zero<<<2,256,0,stream>>>(gsum, 512);
  gn_stats_pm<<<dim3(64,8),256,0,stream>>>(resT, gsum, gssq);
  gn_fin<<<1,256,0,stream>>>(gsum, gssq, statm1, statr1);
  k4_mfma<<<dim3(64,8),256,0,stream>>>(resT, Wdb, statm1, statr1,
                                       gng, gnb, dbng, dbnb, t1);

  // gn2+add x -> gn3 -> out
  gn_stats<<<256,256,0,stream>>>(t1, 4096, statm2, statr2);
  k6_gn_add<<<32768,256,0,stream>>>(t1, x, statm2, statr2, gng, gnb);
  gn_stats<<<256,256,0,stream>>>(t1, 4096, statm3, statr3);
  k8_gn_out<<<32768,256,0,stream>>>(t1, statm3, statr3, gng, gnb, out);
}

// Round 4
// 856.055 us; speedup vs baseline: 2.3020x; 1.9963x over previous
//
#include <hip/hip_runtime.h>
#include <hip/hip_bf16.h>
#include <math.h>

typedef __hip_bfloat16 bf16;
typedef __attribute__((ext_vector_type(8))) short short8_t;
typedef __attribute__((ext_vector_type(4))) short short4_t;
typedef __attribute__((ext_vector_type(4))) float f32x4_t;

#define EPSV 1e-5f
#define BNSC 0.99999500003749968f  // 1/sqrt(1+1e-5)

__device__ __forceinline__ float bf2f(bf16 v){ return __bfloat162float(v); }
__device__ __forceinline__ bf16 f2bf(float v){ return __float2bfloat16(v); }

__device__ __forceinline__ float blk_sum(float v, float* sm){
  int tid = threadIdx.x;
  #pragma unroll
  for(int o=32;o>0;o>>=1) v += __shfl_down(v, o, 64);
  if((tid&63)==0) sm[tid>>6] = v;
  __syncthreads();
  float s = 0.f;
  int nw = blockDim.x>>6;
  for(int i=0;i<nw;i++) s += sm[i];
  __syncthreads();
  return s;
}

__device__ __forceinline__ float softplusf(float x){
  return (x > 20.f) ? x : log1pf(expf(x));
}
__device__ __forceinline__ float siluf(float x){
  return x / (1.f + expf(-x));
}

// generic batched transpose: src (Bn,R,C) -> dst (Bn,C,R)
__global__ void transpose_k(const float* __restrict__ src, float* __restrict__ dst,
                            int Bn, int R, int C){
  int idx = blockIdx.x*256 + threadIdx.x;
  int rc = R*C;
  int total = Bn*rc;
  if(idx >= total) return;
  int d = idx / rc;
  int rem = idx - d*rc;
  int i = rem / C;
  int j = rem - i*C;
  dst[d*rc + j*R + i] = src[idx];
}

// f32 -> bf16 weight convert (keeps [o][c] layout, c contiguous = K-major)
__global__ void wcvt(const float* __restrict__ src, bf16* __restrict__ dst, int n){
  int i = blockIdx.x*256 + threadIdx.x;
  if(i < n) dst[i] = f2bf(src[i]);
}

// R1: per (b,c) slice: col max/min over h, row max/min over w, + pos-emb + idx
__global__ void r1_reduce_pe(const float* __restrict__ x, const float* __restrict__ pe,
                             float* __restrict__ pmax, float* __restrict__ pmin){
  __shared__ float tile[64*65];
  int bc = blockIdx.x;          // b*256 + c
  int b = bc >> 8, c = bc & 255;
  const float* xp = x + ((size_t)bc << 12);
  for(int i=threadIdx.x; i<4096; i+=64)
    tile[(i>>6)*65 + (i&63)] = xp[i];
  __syncthreads();
  int t = threadIdx.x;
  float cmx=-3.4e38f, cmn=3.4e38f; int cax=0, can=0;
  for(int h=0;h<64;h++){
    float v = tile[h*65 + t];
    if(v > cmx){ cmx=v; cax=h; }
    if(v < cmn){ cmn=v; can=h; }
  }
  float rmx=-3.4e38f, rmn=3.4e38f; int rax=0, ran=0;
  for(int w=0;w<64;w++){
    float v = tile[t*65 + w];
    if(v > rmx){ rmx=v; rax=w; }
    if(v < rmn){ rmn=v; ran=w; }
  }
  float coords = fmaxf((t + 0.5f)*0.25f - 0.5f, 0.f);
  int i0 = (int)floorf(coords);
  int i1 = min(i0+1, 15);
  float wg = coords - (float)i0;
  float pos = pe[c*16+i0]*(1.f-wg) + pe[c*16+i1]*wg;
  size_t base_col = ((size_t)b*128 + t)*256 + c;
  size_t base_row = ((size_t)b*128 + 64 + t)*256 + c;
  pmax[base_col] = cmx + pos + (float)cax;
  pmin[base_col] = cmn + pos + (float)can;
  pmax[base_row] = rmx + pos + (float)rax;
  pmin[base_row] = rmn + pos + (float)ran;
}

// row LayerNorm over 256, in place
__global__ void ln_rows(float* __restrict__ buf, const float* __restrict__ g,
                        const float* __restrict__ bb){
  __shared__ float sm[8];
  int row = blockIdx.x, t = threadIdx.x;
  float v = buf[(size_t)row*256 + t];
  float m = blk_sum(v, sm) * (1.f/256.f);
  float dv = v - m;
  float var = blk_sum(dv*dv, sm) * (1.f/256.f);
  buf[(size_t)row*256 + t] = dv * rsqrtf(var + EPSV) * g[t] + bb[t];
}

// M1: xz[rb][l][i] = sum_c u(b,l_eff,c) * in_w[d][i][c]   (WTin is [d][c][i])
__global__ void m1_xz(const float* __restrict__ rmax, const float* __restrict__ rmin,
                      const float* __restrict__ WTin, float* __restrict__ xz){
  __shared__ float ut[16*256];
  int bx = blockIdx.x;                 // 256 blocks: r*64 + b*8 + lt
  int r = bx >> 6, rem = bx & 63, b = rem >> 3, lt = rem & 7;
  int d = r & 1;
  const float* u = (r < 2) ? rmax : rmin;
  bool flip = (r & 1);
  for(int i=threadIdx.x; i<16*256; i+=256){
    int lr = i >> 8, c = i & 255;
    int l = lt*16 + lr;
    int le = flip ? (127 - l) : l;
    ut[i] = u[((size_t)b*128 + le)*256 + c];
  }
  __syncthreads();
  const float* W = WTin + (size_t)d*256*1024;
  size_t rowbase = ((size_t)(r*8 + b)*128 + lt*16)*1024;
  for(int j=0;j<4;j++){
    int i = j*256 + threadIdx.x;
    float acc[16];
    #pragma unroll
    for(int q=0;q<16;q++) acc[q] = 0.f;
    for(int c=0;c<256;c++){
      float wv = W[(size_t)c*1024 + i];
      #pragma unroll
      for(int q=0;q<16;q++) acc[q] += wv * ut[(q<<8) + c];
    }
    #pragma unroll
    for(int q=0;q<16;q++) xz[rowbase + (size_t)q*1024 + i] = acc[q];
  }
}

// M2: causal depthwise conv (k=4) + silu over xh part of xz
__global__ void m2_conv(const float* __restrict__ xz, const float* __restrict__ cw,
                        const float* __restrict__ cb, float* __restrict__ xc){
  int idx = blockIdx.x*256 + threadIdx.x;   // < 4*8*128*512
  int dd = idx & 511;
  int l  = (idx >> 9) & 127;
  int rb = idx >> 16;
  int d = (rb >> 3) & 1;
  const float* base = xz + ((size_t)rb*128)*1024 + dd;  // xh[rb][.][dd]
  float s = cb[d*512 + dd];
  const float* w = cw + (size_t)(d*512 + dd)*4;
  #pragma unroll
  for(int k=0;k<4;k++){
    int ls = l - 3 + k;
    if(ls >= 0) s += base[(size_t)ls*1024] * w[k];
  }
  xc[idx] = siluf(s);
}

// M3: dbl[row][e] = sum_dd xc[row][dd] * xproj[d][e][dd]
__global__ void m3_xproj(const float* __restrict__ xc, const float* __restrict__ xproj,
                         float* __restrict__ dbl){
  __shared__ float row[512];
  int rowid = blockIdx.x;          // 4096
  int d = (rowid >> 10) & 1;
  for(int i=threadIdx.x;i<512;i+=64) row[i] = xc[(size_t)rowid*512 + i];
  __syncthreads();
  if(threadIdx.x < 48){
    const float* wp = xproj + (size_t)(d*48 + threadIdx.x)*512;
    float s = 0.f;
    for(int k=0;k<512;k++) s += row[k]*wp[k];
    dbl[(size_t)rowid*48 + threadIdx.x] = s;
  }
}

// M4: dt[row][dd] = softplus(sum_r dbl[row][r]*dt_w[d][dd][r] + dt_b[d][dd])
__global__ void m4_dt(const float* __restrict__ dbl, const float* __restrict__ dtw,
                      const float* __restrict__ dtbias, float* __restrict__ dt){
  int idx = blockIdx.x*256 + threadIdx.x;   // < 2,097,152
  int dd = idx & 511;
  int rowid = idx >> 9;
  int d = (rowid >> 10) & 1;
  const float* dr = dbl + (size_t)rowid*48;
  const float* wp = dtw + (size_t)(d*512 + dd)*16;
  float s = dtbias[d*512 + dd];
  #pragma unroll
  for(int r=0;r<16;r++) s += dr[r]*wp[r];
  dt[idx] = softplusf(s);
}

// M5: selective scan + D-skip + silu(z) gate -> yb
__global__ void m5_scan(const float* __restrict__ dt, const float* __restrict__ xc,
                        const float* __restrict__ dbl, const float* __restrict__ xz,
                        const float* __restrict__ Alog, const float* __restrict__ Dp,
                        float* __restrict__ yb){
  int bx = blockIdx.x;         // 64: r(2b) | b(3b) | half(1b)
  int r = bx >> 4, b = (bx >> 1) & 7, half = bx & 1;
  int dd = half*256 + threadIdx.x;
  int d = r & 1, rb = r*8 + b;
  float A[16], h[16];
  #pragma unroll
  for(int s=0;s<16;s++){
    A[s] = -expf(Alog[(size_t)(d*512 + dd)*16 + s]);
    h[s] = 0.f;
  }
  float Dv = Dp[d*512 + dd];
  for(int l=0;l<128;l++){
    size_t row = (size_t)rb*128 + l;
    float dtv = dt[row*512 + dd];
    float xcv = xc[row*512 + dd];
    float zgv = xz[row*1024 + 512 + dd];
    const float* dr = dbl + row*48;
    float y = 0.f;
    #pragma unroll
    for(int s=0;s<16;s++){
      h[s] = expf(dtv*A[s])*h[s] + dtv*dr[16+s]*xcv;
      y += h[s]*dr[32+s];
    }
    yb[row*512 + dd] = (y + xcv*Dv) * siluf(zgv);
  }
}

// M6: mo[row][o] = sum_dd yb[row][dd] * out_w[d][o][dd]   (WTout is [d][dd][o])
__global__ void m6_outproj(const float* __restrict__ yb, const float* __restrict__ WTout,
                           float* __restrict__ mo){
  __shared__ float yt[16*512];
  int bx = blockIdx.x;          // 256 blocks
  int r = bx >> 6, rem = bx & 63, b = rem >> 3, lt = rem & 7;
  int d = r & 1, rb = r*8 + b;
  size_t rowbase = ((size_t)rb*128 + lt*16);
  for(int i=threadIdx.x;i<16*512;i+=256){
    int lr = i >> 9, dd = i & 511;
    yt[i] = yb[(rowbase + lr)*512 + dd];
  }
  __syncthreads();
  const float* W = WTout + (size_t)d*512*256;
  float acc[16];
  #pragma unroll
  for(int q=0;q<16;q++) acc[q] = 0.f;
  for(int dd=0;dd<512;dd++){
    float wv = W[(size_t)dd*256 + threadIdx.x];
    #pragma unroll
    for(int q=0;q<16;q++) acc[q] += wv * yt[(q<<9) + dd];
  }
  #pragma unroll
  for(int q=0;q<16;q++)
    mo[(rowbase + q)*256 + threadIdx.x] = acc[q];
}

// M7: res_{max,min}[b][l][o] = [fm[b][l][:] , bm[b][127-l][:]] . proj_w[o][:] + proj_b[o]
__global__ void m7_proj(const float* __restrict__ mo, const float* __restrict__ PT,
                        const float* __restrict__ pb, float* __restrict__ resm,
                        float* __restrict__ resn){
  __shared__ float ct[16*512];
  int bx = blockIdx.x;          // 128: t(1b) | b(3b) | lt(3b)
  int t = bx >> 6, rem = bx & 63, b = rem >> 3, lt = rem & 7;
  int fr = t*2, br = t*2 + 1;
  for(int i=threadIdx.x;i<16*512;i+=256){
    int lr = i >> 9, k = i & 511;
    int l = lt*16 + lr;
    ct[i] = (k < 256)
      ? mo[(((size_t)(fr*8+b)*128) + l)*256 + k]
      : mo[(((size_t)(br*8+b)*128) + (127-l))*256 + (k-256)];
  }
  __syncthreads();
  float acc[16];
  #pragma unroll
  for(int q=0;q<16;q++) acc[q] = 0.f;
  for(int k=0;k<512;k++){
    float pv = PT[(size_t)k*256 + threadIdx.x];
    #pragma unroll
    for(int q=0;q<16;q++) acc[q] += pv * ct[(q<<9) + k];
  }
  float* dst = t ? resn : resm;
  float bias = pb[threadIdx.x];
  #pragma unroll
  for(int q=0;q<16;q++)
    dst[((size_t)b*128 + lt*16 + q)*256 + threadIdx.x] = acc[q] + bias;
}

// K1: stride-2 transposed depthwise 3x3 + BN + ReLU -> zT (bf16, [b][p][c] pixel-major)
// block = (b, h, w-half(64), c-block(64)). LDS-staged input slab, coalesced in/out.
__global__ __launch_bounds__(256)
void k1_deconv_T(const float* __restrict__ x, const float* __restrict__ wdw,
                 const float* __restrict__ g1, const float* __restrict__ b1,
                 bf16* __restrict__ zT){
  __shared__ float in[2*64*33];   // [row][c][iw]: row*2112 + c*33 + iw
  __shared__ bf16 ot[64*80];      // [wi][c] pitch 80 (160 B, 16B-aligned rows)
  int bx = blockIdx.x;            // cb(2b) | half(1b) | h(7b) | b(3b)
  int cb = bx & 3, half = (bx>>2)&1, h = (bx>>3)&127, b = bx>>10;
  int c0 = cb*64, w0 = half*64, iw0 = w0>>1;
  int h_odd = h & 1;
  int ihA = h_odd ? (h-1)>>1 : h>>1;
  int ihB = (h+1)>>1;
  bool hasB = h_odd && (ihB < 64);
  // load phase: zero-padded OOB -> branch-free compute
  for(int i = threadIdx.x; i < 4224; i += 256){
    int row = i / 2112;
    int rem = i - row*2112;
    int c = rem / 33;
    int iw = rem - c*33;
    int ihl = row ? ihB : ihA;
    bool valid = (iw0 + iw < 64) && (row == 0 || hasB);
    in[i] = valid ? x[(((size_t)b*256 + c0 + c)<<12) + (ihl<<6) + iw0 + iw] : 0.f;
  }
  __syncthreads();
  int c = threadIdx.x & 63, g = threadIdx.x >> 6;
  const float* wp = wdw + (c0+c)*9;
  int khA3 = h_odd ? 6 : 3;
  float wA0 = wp[khA3], wA1 = wp[khA3+1], wA2 = wp[khA3+2];
  float wB0 = wp[0],    wB1 = wp[1],      wB2 = wp[2];
  float scale = g1[c0+c]*BNSC, bias = b1[c0+c];
  const float* inA = in + c*33;
  const float* inB = in + 2112 + c*33;
  #pragma unroll
  for(int i=0;i<16;i++){
    int wi = g*16 + i;                 // wi&1 == i&1: compile-time per iteration
    float s;
    if(!(i&1)){
      int iw = wi>>1;
      s = inA[iw]*wA1 + inB[iw]*wB1;
    } else {
      int iwa = (wi-1)>>1, iwb = (wi+1)>>1;
      s = inA[iwa]*wA2 + inA[iwb]*wA0 + inB[iwa]*wB2 + inB[iwb]*wB0;
    }
    ot[wi*80 + c] = f2bf(fmaxf(s*scale + bias, 0.f));
  }
  __syncthreads();
  // write phase: 64 rows x 64 c, short8 per lane-slot
  int rr = threadIdx.x >> 3;          // 0..31
  int co = (threadIdx.x & 7) * 8;     // 0..56
  size_t obase = (((size_t)b*16384) + (size_t)h*128 + w0)*256 + c0;
  #pragma unroll
  for(int pass=0; pass<2; pass++){
    int wi = rr + pass*32;
    short8_t v = *(const short8_t*)&ot[wi*80 + co];
    *(short8_t*)((short*)zT + obase + (size_t)wi*256 + co) = v;
  }
}

// K2 (MFMA): resT[b][p][o] = hsig_gate * clip6(BN(sum_c W[o][c]*zT[b][p][c]))
__global__ __launch_bounds__(256,2)
void k2_mfma(const bf16* __restrict__ zT, const bf16* __restrict__ Wub,
             const float* __restrict__ g2, const float* __restrict__ b2,
             const float* __restrict__ resm, const float* __restrict__ resn,
             bf16* __restrict__ resT){
  __shared__ bf16 zt[64*264];
  int b = blockIdx.y;
  int p0 = blockIdx.x*64;
  int t = threadIdx.x;
  {
    const short* src = (const short*)zT + (((size_t)b*16384 + p0)*256);
    int pr = t>>5;
    int cc = (t&31)*8;
    #pragma unroll
    for(int i=0;i<8;i++){
      int p = pr + i*8;
      short8_t v = *(const short8_t*)(src + (size_t)p*256 + cc);
      *(short8_t*)&zt[p*264 + cc] = v;
    }
  }
  __syncthreads();
  int wv = t>>6, lane = t&63, quad = lane>>4, l16 = lane&15;
  int m0 = wv*64;
  f32x4_t acc[4][4];
  #pragma unroll
  for(int ms=0;ms<4;ms++)
    #pragma unroll
    for(int ns=0;ns<4;ns++) acc[ms][ns] = (f32x4_t){0.f,0.f,0.f,0.f};
  for(int k0=0;k0<256;k0+=32){
    short8_t afr[4], bfr[4];
    const short* wp = (const short*)Wub + (size_t)(m0 + l16)*256 + k0 + quad*8;
    #pragma unroll
    for(int ms=0;ms<4;ms++) afr[ms] = *(const short8_t*)(wp + (size_t)ms*16*256);
    #pragma unroll
    for(int ns=0;ns<4;ns++) bfr[ns] = *(const short8_t*)&zt[(ns*16 + l16)*264 + k0 + quad*8];
    #pragma unroll
    for(int ms=0;ms<4;ms++)
      #pragma unroll
      for(int ns=0;ns<4;ns++)
        acc[ms][ns] = __builtin_amdgcn_mfma_f32_16x16x32_bf16(afr[ms], bfr[ns], acc[ms][ns], 0,0,0);
  }
  #pragma unroll
  for(int ns=0;ns<4;ns++){
    int p = p0 + ns*16 + l16;
    int hh = p>>7, ww = p&127;
    const float* rm = resm + ((size_t)b*128+hh)*256;
    const float* rn = resn + ((size_t)b*128+ww)*256;
    size_t orow = ((size_t)b*16384 + p)*256;
    #pragma unroll
    for(int ms=0;ms<4;ms++){
      int o = m0 + ms*16 + quad*4;
      f32x4_t a = acc[ms][ns];
      f32x4_t gv = *(const f32x4_t*)(g2+o);
      f32x4_t bv = *(const f32x4_t*)(b2+o);
      f32x4_t rmv = *(const f32x4_t*)(rm+o);
      f32x4_t rnv = *(const f32x4_t*)(rn+o);
      alignas(8) bf16 ov[4];
      #pragma unroll
      for(int r=0;r<4;r++){
        float zv = a[r]*(gv[r]*BNSC) + bv[r];
        zv = fminf(fmaxf(zv, 0.f), 6.f);
        float gate = fminf(fmaxf(rmv[r]+rnv[r]+3.f, 0.f), 6.f)*(1.f/6.f);
        ov[r] = f2bf(zv*gate);
      }
      *(short4_t*)((short*)resT + orow + o) = *(const short4_t*)ov;
    }
  }
}

// zero the gn1 accumulators
__global__ void gn_zero(float* __restrict__ p, int n){
  int i = blockIdx.x*256 + threadIdx.x;
  if(i<n) p[i] = 0.f;
}

// GN1 stats over pixel-major resT
__global__ void gn_stats_pm(const bf16* __restrict__ resT, float* __restrict__ sum,
                            float* __restrict__ ssq){
  __shared__ float ls[256], lq[256];
  int b = blockIdx.y, p0 = blockIdx.x*256;
  int c = threadIdx.x;
  const short* src = (const short*)resT + ((size_t)b*16384 + p0)*256 + c;
  float s=0.f, q=0.f;
  for(int i=0;i<256;i++){
    bf16 raw; *(short*)&raw = src[(size_t)i*256];
    float v = bf2f(raw);
    s += v; q += v*v;
  }
  ls[c]=s; lq[c]=q;
  __syncthreads();
  if(c<32){
    float S=0.f,Q=0.f;
    #pragma unroll
    for(int j=0;j<8;j++){ S+=ls[c*8+j]; Q+=lq[c*8+j]; }
    atomicAdd(&sum[b*32+c], S);
    atomicAdd(&ssq[b*32+c], Q);
  }
}

__global__ void gn_fin(const float* __restrict__ sum, const float* __restrict__ ssq,
                       float* __restrict__ statm, float* __restrict__ statr){
  int i = threadIdx.x;
  float m = sum[i] * (1.f/131072.f);
  float var = ssq[i] * (1.f/131072.f) - m*m;
  statm[i] = m;
  statr[i] = rsqrtf(var + EPSV);
}

// K4 (MFMA): t1[b][o][p'] = BN(sum_c Wd[o][c] * gn1(resT[b][2y,2x][c]))
__global__ __launch_bounds__(256,2)
void k4_mfma(const bf16* __restrict__ resT, const bf16* __restrict__ Wdb,
             const float* __restrict__ statm, const float* __restrict__ statr,
             const float* __restrict__ gng, const float* __restrict__ gnb,
             const float* __restrict__ dbg, const float* __restrict__ dbb,
             float* __restrict__ t1){
  __shared__ bf16 at[64*264];
  __shared__ float sc[256], sb[256];
  int b = blockIdx.y;
  int q0 = blockIdx.x*64;
  int t = threadIdx.x;
  {
    int cch = t, g = cch>>3;
    float m = statm[b*32+g], rs = statr[b*32+g];
    float s = rs*gng[cch];
    sc[cch] = s; sb[cch] = gnb[cch] - m*s;
  }
  __syncthreads();
  {
    int pr = t>>5;
    int cc = (t&31)*8;
    #pragma unroll
    for(int i=0;i<8;i++){
      int q = pr + i*8;
      int qq = q0 + q;
      int y = qq>>6, xw = qq&63;
      size_t srow = ((size_t)b*16384 + (size_t)y*256 + xw*2)*256;
      short8_t v = *(const short8_t*)((const short*)resT + srow + cc);
      const bf16* vv = (const bf16*)&v;
      alignas(16) bf16 ov[8];
      #pragma unroll
      for(int j=0;j<8;j++) ov[j] = f2bf(bf2f(vv[j])*sc[cc+j] + sb[cc+j]);
      *(short8_t*)&at[q*264 + cc] = *(const short8_t*)ov;
    }
  }
  __syncthreads();
  int wv = t>>6, lane = t&63, quad = lane>>4, l16 = lane&15;
  int n0 = wv*64;
  f32x4_t acc[4][4];
  #pragma unroll
  for(int ms=0;ms<4;ms++)
    #pragma unroll
    for(int ns=0;ns<4;ns++) acc[ms][ns] = (f32x4_t){0.f,0.f,0.f,0.f};
  for(int k0=0;k0<256;k0+=32){
    short8_t afr[4], bfr[4];
    #pragma unroll
    for(int ms=0;ms<4;ms++) afr[ms] = *(const short8_t*)&at[(ms*16 + l16)*264 + k0 + quad*8];
    const short* wp = (const short*)Wdb + (size_t)(n0 + l16)*256 + k0 + quad*8;
    #pragma unroll
    for(int ns=0;ns<4;ns++) bfr[ns] = *(const short8_t*)(wp + (size_t)ns*16*256);
    #pragma unroll
    for(int ms=0;ms<4;ms++)
      #pragma unroll
      for(int ns=0;ns<4;ns++)
        acc[ms][ns] = __builtin_amdgcn_mfma_f32_16x16x32_bf16(afr[ms], bfr[ns], acc[ms][ns], 0,0,0);
  }
  #pragma unroll
  for(int ns=0;ns<4;ns++){
    int o = n0 + ns*16 + l16;
    float s2 = dbg[o]*BNSC, bb2 = dbb[o];
    float* dst = t1 + (((size_t)b*256 + o) << 12);
    #pragma unroll
    for(int ms=0;ms<4;ms++){
      int ps = q0 + ms*16 + quad*4;
      f32x4_t a = acc[ms][ns];
      f32x4_t ov;
      #pragma unroll
      for(int r=0;r<4;r++) ov[r] = a[r]*s2 + bb2;
      *(f32x4_t*)(dst + ps) = ov;
    }
  }
}

// GN stats over channel-major f32 (t1)
__global__ void gn_stats(const float* __restrict__ src, int HW,
                         float* __restrict__ statm, float* __restrict__ statr){
  __shared__ float sm[8];
  int bg = blockIdx.x;
  int b = bg >> 5, g = bg & 31;
  size_t base = ((size_t)(b*256 + g*8))*(size_t)HW;
  int n = 8*HW;
  const float* p = src + base;
  float s = 0.f, ss = 0.f;
  for(int i=threadIdx.x;i<n;i+=256){ float v = p[i]; s += v; ss += v*v; }
  s = blk_sum(s, sm);
  ss = blk_sum(ss, sm);
  if(threadIdx.x == 0){
    float m = s/(float)n;
    float var = ss/(float)n - m*m;
    statm[bg] = m;
    statr[bg] = rsqrtf(var + EPSV);
  }
}

// K6: t1 = gn2(t1) + x  (in place)
__global__ void k6_gn_add(float* __restrict__ t1, const float* __restrict__ x,
                          const float* __restrict__ statm, const float* __restrict__ statr,
                          const float* __restrict__ gng, const float* __restrict__ gnb){
  int idx = blockIdx.x*256 + threadIdx.x;
  int c = (idx >> 12) & 255, b = idx >> 20, g = c >> 3;
  float m = statm[b*32 + g], rs = statr[b*32 + g];
  t1[idx] = (t1[idx] - m)*rs*gng[c] + gnb[c] + x[idx];
}

// K8: out = gn3(t1)
__global__ void k8_gn_out(const float* __restrict__ t1, const float* __restrict__ statm,
                          const float* __restrict__ statr, const float* __restrict__ gng,
                          const float* __restrict__ gnb, float* __restrict__ out){
  int idx = blockIdx.x*256 + threadIdx.x;
  int c = (idx >> 12) & 255, b = idx >> 20, g = c >> 3;
  float m = statm[b*32 + g], rs = statr[b*32 + g];
  out[idx] = (t1[idx] - m)*rs*gng[c] + gnb[c];
}

extern "C" void kernel_launch(void* const* d_in, const int* in_sizes, int n_in,
                              void* d_out, int out_size, void* d_ws, size_t ws_size,
                              hipStream_t stream){
  const float* x      = (const float*)d_in[0];
  const float* pos    = (const float*)d_in[1];
  const float* ln_g   = (const float*)d_in[2];
  const float* ln_b   = (const float*)d_in[3];
  const float* in_w   = (const float*)d_in[4];
  const float* conv_w = (const float*)d_in[5];
  const float* conv_b = (const float*)d_in[6];
  const float* xproj  = (const float*)d_in[7];
  const float* dt_w   = (const float*)d_in[8];
  const float* dt_b   = (const float*)d_in[9];
  const float* A_log  = (const float*)d_in[10];
  const float* Dp     = (const float*)d_in[11];
  const float* out_w  = (const float*)d_in[12];
  const float* proj_w = (const float*)d_in[13];
  const float* proj_b = (const float*)d_in[14];
  const float* dw_w   = (const float*)d_in[15];
  const float* bn1g   = (const float*)d_in[16];
  const float* bn1b   = (const float*)d_in[17];
  const float* pw_w   = (const float*)d_in[18];
  const float* bn2g   = (const float*)d_in[19];
  const float* bn2b   = (const float*)d_in[20];
  const float* dpw_w  = (const float*)d_in[21];
  const float* dbng   = (const float*)d_in[22];
  const float* dbnb   = (const float*)d_in[23];
  const float* gng    = (const float*)d_in[24];
  const float* gnb    = (const float*)d_in[25];
  float* out = (float*)d_out;

  float* ws = (float*)d_ws;
  bf16*  resT = (bf16*)ws;                       // 33,554,432 bf16 (pixel-major)
  bf16*  zT   = (bf16*)(ws + 16777216);          // 33,554,432 bf16 (pixel-major)
  float* zone = ws + 33554432;
  float* xz   = zone;                            // 4,194,304
  float* xc   = xz  + 4194304;                   // 2,097,152
  float* dbl  = xc  + 2097152;                   //   196,608
  float* dtb  = dbl + 196608;                    // 2,097,152
  float* yb   = dtb + 2097152;                   // 2,097,152
  float* t1   = zone;                            // overlay (8,388,608 <= 10,682,368)
  float* mo   = zone + 10682368;                 // 1,048,576
  float* resm = mo   + 1048576;                  //   262,144
  float* resn = resm + 262144;                   //   262,144
  float* pmax = resn + 262144;                   //   262,144
  float* pmin = pmax + 262144;                   //   262,144
  float* WTin = pmin + 262144;                   //   524,288
  float* WTout= WTin + 524288;                   //   262,144
  float* PT   = WTout+ 262144;                   //   131,072
  bf16*  Wub  = (bf16*)(PT + 131072);            //    65,536 bf16
  bf16*  Wdb  = (bf16*)(PT + 131072 + 32768);    //    65,536 bf16
  float* stat = PT + 131072 + 65536;             //     2,048
  float* statm1 = stat;        float* statr1 = stat + 256;
  float* statm2 = stat + 512;  float* statr2 = stat + 768;
  float* statm3 = stat + 1024; float* statr3 = stat + 1280;
  float* gsum   = stat + 1536; float* gssq   = stat + 1792;

  // weight prep
  transpose_k<<<(2*1024*256+255)/256,256,0,stream>>>(in_w,  WTin,  2, 1024, 256);
  transpose_k<<<(2*256*512+255)/256, 256,0,stream>>>(out_w, WTout, 2, 256, 512);
  transpose_k<<<(256*512+255)/256,   256,0,stream>>>(proj_w,PT,    1, 256, 512);
  wcvt<<<256,256,0,stream>>>(pw_w,  Wub, 65536);
  wcvt<<<256,256,0,stream>>>(dpw_w, Wdb, 65536);

  // reductions + pos-emb + LN -> result_max / result_min (b,128,256)
  r1_reduce_pe<<<2048,64,0,stream>>>(x, pos, pmax, pmin);
  ln_rows<<<1024,256,0,stream>>>(pmax, ln_g, ln_b);
  ln_rows<<<1024,256,0,stream>>>(pmin, ln_g, ln_b);

  // mamba (4 runs batched)
  m1_xz<<<256,256,0,stream>>>(pmax, pmin, WTin, xz);
  m2_conv<<<8192,256,0,stream>>>(xz, conv_w, conv_b, xc);
  m3_xproj<<<4096,64,0,stream>>>(xc, xproj, dbl);
  m4_dt<<<8192,256,0,stream>>>(dbl, dt_w, dt_b, dtb);
  m5_scan<<<64,256,0,stream>>>(dtb, xc, dbl, xz, A_log, Dp, yb);
  m6_outproj<<<256,256,0,stream>>>(yb, WTout, mo);
  ln_rows<<<4096,256,0,stream>>>(mo, ln_g, ln_b);
  m7_proj<<<128,256,0,stream>>>(mo, PT, proj_b, resm, resn);
  ln_rows<<<1024,256,0,stream>>>(resm, ln_g, ln_b);
  ln_rows<<<1024,256,0,stream>>>(resn, ln_g, ln_b);

  // upsample branch (pixel-major) + MFMA pointwise + gate
  k1_deconv_T<<<8192,256,0,stream>>>(x, dw_w, bn1g, bn1b, zT);
  k2_mfma<<<dim3(256,8),256,0,stream>>>(zT, Wub, bn2g, bn2b, resm, resn, resT);

  // gn1 stats (pixel-major) -> MFMA downsample pointwise + BN
  gn_zero<<<2,256,0,stream>>>(gsum, 512);
  gn_stats_pm<<<dim3(64,8),256,0,stream>>>(resT, gsum, gssq);
  gn_fin<<<1,256,0,stream>>>(gsum, gssq, statm1, statr1);
  k4_mfma<<<dim3(64,8),256,0,stream>>>(resT, Wdb, statm1, statr1,
                                       gng, gnb, dbng, dbnb, t1);

  // gn2+add x -> gn3 -> out
  gn_stats<<<256,256,0,stream>>>(t1, 4096, statm2, statr2);
  k6_gn_add<<<32768,256,0,stream>>>(t1, x, statm2, statr2, gng, gnb);
  gn_stats<<<256,256,0,stream>>>(t1, 4096, statm3, statr3);
  k8_gn_out<<<32768,256,0,stream>>>(t1, statm3, statr3, gng, gnb, out);
}

// Round 5
// 639.310 us; speedup vs baseline: 3.0824x; 1.3390x over previous
//
#include <hip/hip_runtime.h>
#include <hip/hip_bf16.h>
#include <math.h>

typedef __hip_bfloat16 bf16;
typedef __attribute__((ext_vector_type(8))) short short8_t;
typedef __attribute__((ext_vector_type(4))) short short4_t;
typedef __attribute__((ext_vector_type(4))) float f32x4_t;

#define EPSV 1e-5f
#define BNSC 0.99999500003749968f  // 1/sqrt(1+1e-5)

__device__ __forceinline__ float bf2f(bf16 v){ return __bfloat162float(v); }
__device__ __forceinline__ bf16 f2bf(float v){ return __float2bfloat16(v); }

__device__ __forceinline__ float blk_sum(float v, float* sm){
  int tid = threadIdx.x;
  #pragma unroll
  for(int o=32;o>0;o>>=1) v += __shfl_down(v, o, 64);
  if((tid&63)==0) sm[tid>>6] = v;
  __syncthreads();
  float s = 0.f;
  int nw = blockDim.x>>6;
  for(int i=0;i<nw;i++) s += sm[i];
  __syncthreads();
  return s;
}

// fast transcendental versions (v_exp_f32 / v_log_f32)
__device__ __forceinline__ float softplusf(float x){
  return (x > 20.f) ? x : __logf(1.f + __expf(x));
}
__device__ __forceinline__ float siluf(float x){
  return x / (1.f + __expf(-x));
}

// generic batched transpose: src (Bn,R,C) -> dst (Bn,C,R)
__global__ void transpose_k(const float* __restrict__ src, float* __restrict__ dst,
                            int Bn, int R, int C){
  int idx = blockIdx.x*256 + threadIdx.x;
  int rc = R*C;
  int total = Bn*rc;
  if(idx >= total) return;
  int d = idx / rc;
  int rem = idx - d*rc;
  int i = rem / C;
  int j = rem - i*C;
  dst[d*rc + j*R + i] = src[idx];
}

// f32 -> bf16 weight convert (keeps layout; K stays contiguous)
__global__ void wcvt(const float* __restrict__ src, bf16* __restrict__ dst, int n){
  int i = blockIdx.x*256 + threadIdx.x;
  if(i < n) dst[i] = f2bf(src[i]);
}

// R1: per (b,c) slice: col max/min over h, row max/min over w, + pos-emb + idx
__global__ void r1_reduce_pe(const float* __restrict__ x, const float* __restrict__ pe,
                             float* __restrict__ pmax, float* __restrict__ pmin){
  __shared__ float tile[64*65];
  int bc = blockIdx.x;          // b*256 + c
  int b = bc >> 8, c = bc & 255;
  const float* xp = x + ((size_t)bc << 12);
  for(int i=threadIdx.x; i<4096; i+=64)
    tile[(i>>6)*65 + (i&63)] = xp[i];
  __syncthreads();
  int t = threadIdx.x;
  float cmx=-3.4e38f, cmn=3.4e38f; int cax=0, can=0;
  for(int h=0;h<64;h++){
    float v = tile[h*65 + t];
    if(v > cmx){ cmx=v; cax=h; }
    if(v < cmn){ cmn=v; can=h; }
  }
  float rmx=-3.4e38f, rmn=3.4e38f; int rax=0, ran=0;
  for(int w=0;w<64;w++){
    float v = tile[t*65 + w];
    if(v > rmx){ rmx=v; rax=w; }
    if(v < rmn){ rmn=v; ran=w; }
  }
  float coords = fmaxf((t + 0.5f)*0.25f - 0.5f, 0.f);
  int i0 = (int)floorf(coords);
  int i1 = min(i0+1, 15);
  float wg = coords - (float)i0;
  float pos = pe[c*16+i0]*(1.f-wg) + pe[c*16+i1]*wg;
  size_t base_col = ((size_t)b*128 + t)*256 + c;
  size_t base_row = ((size_t)b*128 + 64 + t)*256 + c;
  pmax[base_col] = cmx + pos + (float)cax;
  pmin[base_col] = cmn + pos + (float)can;
  pmax[base_row] = rmx + pos + (float)rax;
  pmin[base_row] = rmn + pos + (float)ran;
}

// row LayerNorm over 256, in place; optional bf16 copy out
__global__ void ln_rows(float* __restrict__ buf, const float* __restrict__ g,
                        const float* __restrict__ bb, bf16* __restrict__ bout){
  __shared__ float sm[8];
  int row = blockIdx.x, t = threadIdx.x;
  float v = buf[(size_t)row*256 + t];
  float m = blk_sum(v, sm) * (1.f/256.f);
  float dv = v - m;
  float var = blk_sum(dv*dv, sm) * (1.f/256.f);
  float r = dv * rsqrtf(var + EPSV) * g[t] + bb[t];
  buf[(size_t)row*256 + t] = r;
  if(bout) bout[(size_t)row*256 + t] = f2bf(r);
}

// M1 (MFMA): xz[rb][l][i] = sum_c u_bf(b,l_eff,c) * in_w_bf[d][i][c]
// block: r(2)|b(3)|lt(1)|it(2): 64 l-rows x 256 i, K=256
__global__ __launch_bounds__(256,2)
void m1_mfma(const bf16* __restrict__ ubmax, const bf16* __restrict__ ubmin,
             const bf16* __restrict__ Win, float* __restrict__ xz){
  __shared__ bf16 att[64*264];
  int bx = blockIdx.x;
  int it = bx & 3, lt = (bx>>2)&1, b = (bx>>3)&7, r = bx>>6;
  int d = r & 1;
  const bf16* u = (r < 2) ? ubmax : ubmin;
  int flip = r & 1;
  int t = threadIdx.x;
  {
    int pr = t>>5, cc = (t&31)*8;
    #pragma unroll
    for(int i=0;i<8;i++){
      int p = pr + i*8;
      int l = lt*64 + p;
      int le = flip ? (127 - l) : l;
      short8_t v = *(const short8_t*)((const short*)u + ((size_t)(b*128 + le))*256 + cc);
      *(short8_t*)&att[p*264 + cc] = v;
    }
  }
  __syncthreads();
  int wv = t>>6, lane = t&63, quad = lane>>4, l16 = lane&15;
  int m0 = wv*64;
  f32x4_t acc[4][4];
  #pragma unroll
  for(int ms=0;ms<4;ms++)
    #pragma unroll
    for(int ns=0;ns<4;ns++) acc[ms][ns] = (f32x4_t){0.f,0.f,0.f,0.f};
  const short* wbase = (const short*)Win + ((size_t)d*1024 + it*256)*256;
  for(int k0=0;k0<256;k0+=32){
    short8_t afr[4], bfr[4];
    #pragma unroll
    for(int ms=0;ms<4;ms++)
      afr[ms] = *(const short8_t*)(wbase + (size_t)(m0 + ms*16 + l16)*256 + k0 + quad*8);
    #pragma unroll
    for(int ns=0;ns<4;ns++)
      bfr[ns] = *(const short8_t*)&att[(ns*16 + l16)*264 + k0 + quad*8];
    #pragma unroll
    for(int ms=0;ms<4;ms++)
      #pragma unroll
      for(int ns=0;ns<4;ns++)
        acc[ms][ns] = __builtin_amdgcn_mfma_f32_16x16x32_bf16(afr[ms], bfr[ns], acc[ms][ns], 0,0,0);
  }
  int rb = r*8 + b;
  #pragma unroll
  for(int ns=0;ns<4;ns++){
    int l = lt*64 + ns*16 + l16;
    float* dst = xz + ((size_t)rb*128 + l)*1024 + it*256;
    #pragma unroll
    for(int ms=0;ms<4;ms++){
      int i = m0 + ms*16 + quad*4;
      *(f32x4_t*)(dst + i) = acc[ms][ns];
    }
  }
}

// M2: causal depthwise conv (k=4) + silu over xh part of xz
__global__ void m2_conv(const float* __restrict__ xz, const float* __restrict__ cw,
                        const float* __restrict__ cb, float* __restrict__ xc){
  int idx = blockIdx.x*256 + threadIdx.x;   // < 4*8*128*512
  int dd = idx & 511;
  int l  = (idx >> 9) & 127;
  int rb = idx >> 16;
  int d = (rb >> 3) & 1;
  const float* base = xz + ((size_t)rb*128)*1024 + dd;
  float s = cb[d*512 + dd];
  const float* w = cw + (size_t)(d*512 + dd)*4;
  #pragma unroll
  for(int k=0;k<4;k++){
    int ls = l - 3 + k;
    if(ls >= 0) s += base[(size_t)ls*1024] * w[k];
  }
  xc[idx] = siluf(s);
}

// M3: dbl[row][e] = sum_dd xc[row][dd] * xproj[d][e][dd]
__global__ void m3_xproj(const float* __restrict__ xc, const float* __restrict__ xproj,
                         float* __restrict__ dbl){
  __shared__ float row[512];
  int rowid = blockIdx.x;          // 4096
  int d = (rowid >> 10) & 1;
  for(int i=threadIdx.x;i<512;i+=64) row[i] = xc[(size_t)rowid*512 + i];
  __syncthreads();
  if(threadIdx.x < 48){
    const float* wp = xproj + (size_t)(d*48 + threadIdx.x)*512;
    float s = 0.f;
    for(int k=0;k<512;k++) s += row[k]*wp[k];
    dbl[(size_t)rowid*48 + threadIdx.x] = s;
  }
}

// M4: dt[row][dd] = softplus(sum_r dbl[row][r]*dt_w[d][dd][r] + dt_b[d][dd])
__global__ void m4_dt(const float* __restrict__ dbl, const float* __restrict__ dtw,
                      const float* __restrict__ dtbias, float* __restrict__ dt){
  int idx = blockIdx.x*256 + threadIdx.x;   // < 2,097,152
  int dd = idx & 511;
  int rowid = idx >> 9;
  int d = (rowid >> 10) & 1;
  const float* dr = dbl + (size_t)rowid*48;
  const float* wp = dtw + (size_t)(d*512 + dd)*16;
  float s = dtbias[d*512 + dd];
  #pragma unroll
  for(int r=0;r<16;r++) s += dr[r]*wp[r];
  dt[idx] = softplusf(s);
}

// M5: selective scan + D-skip + silu(z) gate -> yb (bf16)
__global__ void m5_scan(const float* __restrict__ dt, const float* __restrict__ xc,
                        const float* __restrict__ dbl, const float* __restrict__ xz,
                        const float* __restrict__ Alog, const float* __restrict__ Dp,
                        bf16* __restrict__ ybb){
  int bx = blockIdx.x;         // 64: r(2b) | b(3b) | half(1b)
  int r = bx >> 4, b = (bx >> 1) & 7, half = bx & 1;
  int dd = half*256 + threadIdx.x;
  int d = r & 1, rb = r*8 + b;
  float A[16], h[16];
  #pragma unroll
  for(int s=0;s<16;s++){
    A[s] = -__expf(Alog[(size_t)(d*512 + dd)*16 + s]);
    h[s] = 0.f;
  }
  float Dv = Dp[d*512 + dd];
  for(int l=0;l<128;l++){
    size_t row = (size_t)rb*128 + l;
    float dtv = dt[row*512 + dd];
    float xcv = xc[row*512 + dd];
    float zgv = xz[row*1024 + 512 + dd];
    const float* dr = dbl + row*48;
    float y = 0.f;
    float bx_ = dtv*xcv;
    #pragma unroll
    for(int s=0;s<16;s++){
      h[s] = __expf(dtv*A[s])*h[s] + bx_*dr[16+s];
      y += h[s]*dr[32+s];
    }
    ybb[row*512 + dd] = f2bf((y + xcv*Dv) * siluf(zgv));
  }
}

// M6 (MFMA): mo[row][o] = sum_dd yb_bf[row][dd] * out_w_bf[d][o][dd]
// block: r(2)|b(3)|lt(1): 64 rows x 256 o, K=512
__global__ __launch_bounds__(256,2)
void m6_mfma(const bf16* __restrict__ ybb, const bf16* __restrict__ Wout,
             float* __restrict__ mo){
  __shared__ bf16 ybt[64*520];
  int bx = blockIdx.x;
  int lt = bx & 1, b = (bx>>1)&7, r = bx>>4;
  int d = r & 1, rb = r*8 + b;
  size_t rowbase = (size_t)rb*128 + lt*64;
  int t = threadIdx.x;
  for(int i=t;i<4096;i+=256){            // slots: row*64 + c8
    int row = i>>6, c8 = (i&63)*8;
    short8_t v = *(const short8_t*)((const short*)ybb + (rowbase + row)*512 + c8);
    *(short8_t*)&ybt[row*520 + c8] = v;
  }
  __syncthreads();
  int wv = t>>6, lane = t&63, quad = lane>>4, l16 = lane&15;
  int m0 = wv*64;
  f32x4_t acc[4][4];
  #pragma unroll
  for(int ms=0;ms<4;ms++)
    #pragma unroll
    for(int ns=0;ns<4;ns++) acc[ms][ns] = (f32x4_t){0.f,0.f,0.f,0.f};
  const short* wbase = (const short*)Wout + (size_t)d*256*512;
  for(int k0=0;k0<512;k0+=32){
    short8_t afr[4], bfr[4];
    #pragma unroll
    for(int ms=0;ms<4;ms++)
      afr[ms] = *(const short8_t*)(wbase + (size_t)(m0 + ms*16 + l16)*512 + k0 + quad*8);
    #pragma unroll
    for(int ns=0;ns<4;ns++)
      bfr[ns] = *(const short8_t*)&ybt[(ns*16 + l16)*520 + k0 + quad*8];
    #pragma unroll
    for(int ms=0;ms<4;ms++)
      #pragma unroll
      for(int ns=0;ns<4;ns++)
        acc[ms][ns] = __builtin_amdgcn_mfma_f32_16x16x32_bf16(afr[ms], bfr[ns], acc[ms][ns], 0,0,0);
  }
  #pragma unroll
  for(int ns=0;ns<4;ns++){
    int l = ns*16 + l16;
    float* dst = mo + (rowbase + l)*256;
    #pragma unroll
    for(int ms=0;ms<4;ms++){
      int o = m0 + ms*16 + quad*4;
      *(f32x4_t*)(dst + o) = acc[ms][ns];
    }
  }
}

// M7: res_{max,min}[b][l][o] = [fm[b][l][:] , bm[b][127-l][:]] . proj_w[o][:] + proj_b[o]
__global__ void m7_proj(const float* __restrict__ mo, const float* __restrict__ PT,
                        const float* __restrict__ pb, float* __restrict__ resm,
                        float* __restrict__ resn){
  __shared__ float ct[16*512];
  int bx = blockIdx.x;          // 128: t(1b) | b(3b) | lt(3b)
  int t = bx >> 6, rem = bx & 63, b = rem >> 3, lt = rem & 7;
  int fr = t*2, br = t*2 + 1;
  for(int i=threadIdx.x;i<16*512;i+=256){
    int lr = i >> 9, k = i & 511;
    int l = lt*16 + lr;
    ct[i] = (k < 256)
      ? mo[(((size_t)(fr*8+b)*128) + l)*256 + k]
      : mo[(((size_t)(br*8+b)*128) + (127-l))*256 + (k-256)];
  }
  __syncthreads();
  float acc[16];
  #pragma unroll
  for(int q=0;q<16;q++) acc[q] = 0.f;
  for(int k=0;k<512;k++){
    float pv = PT[(size_t)k*256 + threadIdx.x];
    #pragma unroll
    for(int q=0;q<16;q++) acc[q] += pv * ct[(q<<9) + k];
  }
  float* dst = t ? resn : resm;
  float bias = pb[threadIdx.x];
  #pragma unroll
  for(int q=0;q<16;q++)
    dst[((size_t)b*128 + lt*16 + q)*256 + threadIdx.x] = acc[q] + bias;
}

// K1: stride-2 transposed depthwise 3x3 + BN + ReLU -> zT (bf16, [b][p][c] pixel-major)
__global__ __launch_bounds__(256)
void k1_deconv_T(const float* __restrict__ x, const float* __restrict__ wdw,
                 const float* __restrict__ g1, const float* __restrict__ b1,
                 bf16* __restrict__ zT){
  __shared__ float in[2*64*33];
  __shared__ bf16 ot[64*80];
  int bx = blockIdx.x;            // cb(2b) | half(1b) | h(7b) | b(3b)
  int cb = bx & 3, half = (bx>>2)&1, h = (bx>>3)&127, b = bx>>10;
  int c0 = cb*64, w0 = half*64, iw0 = w0>>1;
  int h_odd = h & 1;
  int ihA = h_odd ? (h-1)>>1 : h>>1;
  int ihB = (h+1)>>1;
  bool hasB = h_odd && (ihB < 64);
  for(int i = threadIdx.x; i < 4224; i += 256){
    int row = i / 2112;
    int rem = i - row*2112;
    int c = rem / 33;
    int iw = rem - c*33;
    int ihl = row ? ihB : ihA;
    bool valid = (iw0 + iw < 64) && (row == 0 || hasB);
    in[i] = valid ? x[(((size_t)b*256 + c0 + c)<<12) + (ihl<<6) + iw0 + iw] : 0.f;
  }
  __syncthreads();
  int c = threadIdx.x & 63, g = threadIdx.x >> 6;
  const float* wp = wdw + (c0+c)*9;
  int khA3 = h_odd ? 6 : 3;
  float wA0 = wp[khA3], wA1 = wp[khA3+1], wA2 = wp[khA3+2];
  float wB0 = wp[0],    wB1 = wp[1],      wB2 = wp[2];
  float scale = g1[c0+c]*BNSC, bias = b1[c0+c];
  const float* inA = in + c*33;
  const float* inB = in + 2112 + c*33;
  #pragma unroll
  for(int i=0;i<16;i++){
    int wi = g*16 + i;
    float s;
    if(!(i&1)){
      int iw = wi>>1;
      s = inA[iw]*wA1 + inB[iw]*wB1;
    } else {
      int iwa = (wi-1)>>1, iwb = (wi+1)>>1;
      s = inA[iwa]*wA2 + inA[iwb]*wA0 + inB[iwa]*wB2 + inB[iwb]*wB0;
    }
    ot[wi*80 + c] = f2bf(fmaxf(s*scale + bias, 0.f));
  }
  __syncthreads();
  int rr = threadIdx.x >> 3;
  int co = (threadIdx.x & 7) * 8;
  size_t obase = (((size_t)b*16384) + (size_t)h*128 + w0)*256 + c0;
  #pragma unroll
  for(int pass=0; pass<2; pass++){
    int wi = rr + pass*32;
    short8_t v = *(const short8_t*)&ot[wi*80 + co];
    *(short8_t*)((short*)zT + obase + (size_t)wi*256 + co) = v;
  }
}

// K2 (MFMA): resT[b][p][o] = hsig_gate * clip6(BN(sum_c W[o][c]*zT[b][p][c]))
__global__ __launch_bounds__(256,2)
void k2_mfma(const bf16* __restrict__ zT, const bf16* __restrict__ Wub,
             const float* __restrict__ g2, const float* __restrict__ b2,
             const float* __restrict__ resm, const float* __restrict__ resn,
             bf16* __restrict__ resT){
  __shared__ bf16 zt[64*264];
  int b = blockIdx.y;
  int p0 = blockIdx.x*64;
  int t = threadIdx.x;
  {
    const short* src = (const short*)zT + (((size_t)b*16384 + p0)*256);
    int pr = t>>5;
    int cc = (t&31)*8;
    #pragma unroll
    for(int i=0;i<8;i++){
      int p = pr + i*8;
      short8_t v = *(const short8_t*)(src + (size_t)p*256 + cc);
      *(short8_t*)&zt[p*264 + cc] = v;
    }
  }
  __syncthreads();
  int wv = t>>6, lane = t&63, quad = lane>>4, l16 = lane&15;
  int m0 = wv*64;
  f32x4_t acc[4][4];
  #pragma unroll
  for(int ms=0;ms<4;ms++)
    #pragma unroll
    for(int ns=0;ns<4;ns++) acc[ms][ns] = (f32x4_t){0.f,0.f,0.f,0.f};
  for(int k0=0;k0<256;k0+=32){
    short8_t afr[4], bfr[4];
    const short* wp = (const short*)Wub + (size_t)(m0 + l16)*256 + k0 + quad*8;
    #pragma unroll
    for(int ms=0;ms<4;ms++) afr[ms] = *(const short8_t*)(wp + (size_t)ms*16*256);
    #pragma unroll
    for(int ns=0;ns<4;ns++) bfr[ns] = *(const short8_t*)&zt[(ns*16 + l16)*264 + k0 + quad*8];
    #pragma unroll
    for(int ms=0;ms<4;ms++)
      #pragma unroll
      for(int ns=0;ns<4;ns++)
        acc[ms][ns] = __builtin_amdgcn_mfma_f32_16x16x32_bf16(afr[ms], bfr[ns], acc[ms][ns], 0,0,0);
  }
  #pragma unroll
  for(int ns=0;ns<4;ns++){
    int p = p0 + ns*16 + l16;
    int hh = p>>7, ww = p&127;
    const float* rm = resm + ((size_t)b*128+hh)*256;
    const float* rn = resn + ((size_t)b*128+ww)*256;
    size_t orow = ((size_t)b*16384 + p)*256;
    #pragma unroll
    for(int ms=0;ms<4;ms++){
      int o = m0 + ms*16 + quad*4;
      f32x4_t a = acc[ms][ns];
      f32x4_t gv = *(const f32x4_t*)(g2+o);
      f32x4_t bv = *(const f32x4_t*)(b2+o);
      f32x4_t rmv = *(const f32x4_t*)(rm+o);
      f32x4_t rnv = *(const f32x4_t*)(rn+o);
      alignas(8) bf16 ov[4];
      #pragma unroll
      for(int r=0;r<4;r++){
        float zv = a[r]*(gv[r]*BNSC) + bv[r];
        zv = fminf(fmaxf(zv, 0.f), 6.f);
        float gate = fminf(fmaxf(rmv[r]+rnv[r]+3.f, 0.f), 6.f)*(1.f/6.f);
        ov[r] = f2bf(zv*gate);
      }
      *(short4_t*)((short*)resT + orow + o) = *(const short4_t*)ov;
    }
  }
}

// zero the gn1 accumulators
__global__ void gn_zero(float* __restrict__ p, int n){
  int i = blockIdx.x*256 + threadIdx.x;
  if(i<n) p[i] = 0.f;
}

// GN1 stats over pixel-major resT
__global__ void gn_stats_pm(const bf16* __restrict__ resT, float* __restrict__ sum,
                            float* __restrict__ ssq){
  __shared__ float ls[256], lq[256];
  int b = blockIdx.y, p0 = blockIdx.x*256;
  int c = threadIdx.x;
  const short* src = (const short*)resT + ((size_t)b*16384 + p0)*256 + c;
  float s=0.f, q=0.f;
  for(int i=0;i<256;i++){
    bf16 raw; *(short*)&raw = src[(size_t)i*256];
    float v = bf2f(raw);
    s += v; q += v*v;
  }
  ls[c]=s; lq[c]=q;
  __syncthreads();
  if(c<32){
    float S=0.f,Q=0.f;
    #pragma unroll
    for(int j=0;j<8;j++){ S+=ls[c*8+j]; Q+=lq[c*8+j]; }
    atomicAdd(&sum[b*32+c], S);
    atomicAdd(&ssq[b*32+c], Q);
  }
}

__global__ void gn_fin(const float* __restrict__ sum, const float* __restrict__ ssq,
                       float* __restrict__ statm, float* __restrict__ statr){
  int i = threadIdx.x;
  float m = sum[i] * (1.f/131072.f);
  float var = ssq[i] * (1.f/131072.f) - m*m;
  statm[i] = m;
  statr[i] = rsqrtf(var + EPSV);
}

// K4 (MFMA): t1[b][o][p'] = BN(sum_c Wd[o][c] * gn1(resT[b][2y,2x][c]))
__global__ __launch_bounds__(256,2)
void k4_mfma(const bf16* __restrict__ resT, const bf16* __restrict__ Wdb,
             const float* __restrict__ statm, const float* __restrict__ statr,
             const float* __restrict__ gng, const float* __restrict__ gnb,
             const float* __restrict__ dbg, const float* __restrict__ dbb,
             float* __restrict__ t1){
  __shared__ bf16 at[64*264];
  __shared__ float sc[256], sb[256];
  int b = blockIdx.y;
  int q0 = blockIdx.x*64;
  int t = threadIdx.x;
  {
    int cch = t, g = cch>>3;
    float m = statm[b*32+g], rs = statr[b*32+g];
    float s = rs*gng[cch];
    sc[cch] = s; sb[cch] = gnb[cch] - m*s;
  }
  __syncthreads();
  {
    int pr = t>>5;
    int cc = (t&31)*8;
    #pragma unroll
    for(int i=0;i<8;i++){
      int q = pr + i*8;
      int qq = q0 + q;
      int y = qq>>6, xw = qq&63;
      size_t srow = ((size_t)b*16384 + (size_t)y*256 + xw*2)*256;
      short8_t v = *(const short8_t*)((const short*)resT + srow + cc);
      const bf16* vv = (const bf16*)&v;
      alignas(16) bf16 ov[8];
      #pragma unroll
      for(int j=0;j<8;j++) ov[j] = f2bf(bf2f(vv[j])*sc[cc+j] + sb[cc+j]);
      *(short8_t*)&at[q*264 + cc] = *(const short8_t*)ov;
    }
  }
  __syncthreads();
  int wv = t>>6, lane = t&63, quad = lane>>4, l16 = lane&15;
  int n0 = wv*64;
  f32x4_t acc[4][4];
  #pragma unroll
  for(int ms=0;ms<4;ms++)
    #pragma unroll
    for(int ns=0;ns<4;ns++) acc[ms][ns] = (f32x4_t){0.f,0.f,0.f,0.f};
  for(int k0=0;k0<256;k0+=32){
    short8_t afr[4], bfr[4];
    #pragma unroll
    for(int ms=0;ms<4;ms++) afr[ms] = *(const short8_t*)&at[(ms*16 + l16)*264 + k0 + quad*8];
    const short* wp = (const short*)Wdb + (size_t)(n0 + l16)*256 + k0 + quad*8;
    #pragma unroll
    for(int ns=0;ns<4;ns++) bfr[ns] = *(const short8_t*)(wp + (size_t)ns*16*256);
    #pragma unroll
    for(int ms=0;ms<4;ms++)
      #pragma unroll
      for(int ns=0;ns<4;ns++)
        acc[ms][ns] = __builtin_amdgcn_mfma_f32_16x16x32_bf16(afr[ms], bfr[ns], acc[ms][ns], 0,0,0);
  }
  #pragma unroll
  for(int ns=0;ns<4;ns++){
    int o = n0 + ns*16 + l16;
    float s2 = dbg[o]*BNSC, bb2 = dbb[o];
    float* dst = t1 + (((size_t)b*256 + o) << 12);
    #pragma unroll
    for(int ms=0;ms<4;ms++){
      int ps = q0 + ms*16 + quad*4;
      f32x4_t a = acc[ms][ns];
      f32x4_t ov;
      #pragma unroll
      for(int r=0;r<4;r++) ov[r] = a[r]*s2 + bb2;
      *(f32x4_t*)(dst + ps) = ov;
    }
  }
}

// GN stats over channel-major f32 (t1)
__global__ void gn_stats(const float* __restrict__ src, int HW,
                         float* __restrict__ statm, float* __restrict__ statr){
  __shared__ float sm[8];
  int bg = blockIdx.x;
  int b = bg >> 5, g = bg & 31;
  size_t base = ((size_t)(b*256 + g*8))*(size_t)HW;
  int n = 8*HW;
  const float* p = src + base;
  float s = 0.f, ss = 0.f;
  for(int i=threadIdx.x;i<n;i+=256){ float v = p[i]; s += v; ss += v*v; }
  s = blk_sum(s, sm);
  ss = blk_sum(ss, sm);
  if(threadIdx.x == 0){
    float m = s/(float)n;
    float var = ss/(float)n - m*m;
    statm[bg] = m;
    statr[bg] = rsqrtf(var + EPSV);
  }
}

// K6: t1 = gn2(t1) + x  (in place)
__global__ void k6_gn_add(float* __restrict__ t1, const float* __restrict__ x,
                          const float* __restrict__ statm, const float* __restrict__ statr,
                          const float* __restrict__ gng, const float* __restrict__ gnb){
  int idx = blockIdx.x*256 + threadIdx.x;
  int c = (idx >> 12) & 255, b = idx >> 20, g = c >> 3;
  float m = statm[b*32 + g], rs = statr[b*32 + g];
  t1[idx] = (t1[idx] - m)*rs*gng[c] + gnb[c] + x[idx];
}

// K8: out = gn3(t1)
__global__ void k8_gn_out(const float* __restrict__ t1, const float* __restrict__ statm,
                          const float* __restrict__ statr, const float* __restrict__ gng,
                          const float* __restrict__ gnb, float* __restrict__ out){
  int idx = blockIdx.x*256 + threadIdx.x;
  int c = (idx >> 12) & 255, b = idx >> 20, g = c >> 3;
  float m = statm[b*32 + g], rs = statr[b*32 + g];
  out[idx] = (t1[idx] - m)*rs*gng[c] + gnb[c];
}

extern "C" void kernel_launch(void* const* d_in, const int* in_sizes, int n_in,
                              void* d_out, int out_size, void* d_ws, size_t ws_size,
                              hipStream_t stream){
  const float* x      = (const float*)d_in[0];
  const float* pos    = (const float*)d_in[1];
  const float* ln_g   = (const float*)d_in[2];
  const float* ln_b   = (const float*)d_in[3];
  const float* in_w   = (const float*)d_in[4];
  const float* conv_w = (const float*)d_in[5];
  const float* conv_b = (const float*)d_in[6];
  const float* xproj  = (const float*)d_in[7];
  const float* dt_w   = (const float*)d_in[8];
  const float* dt_b   = (const float*)d_in[9];
  const float* A_log  = (const float*)d_in[10];
  const float* Dp     = (const float*)d_in[11];
  const float* out_w  = (const float*)d_in[12];
  const float* proj_w = (const float*)d_in[13];
  const float* proj_b = (const float*)d_in[14];
  const float* dw_w   = (const float*)d_in[15];
  const float* bn1g   = (const float*)d_in[16];
  const float* bn1b   = (const float*)d_in[17];
  const float* pw_w   = (const float*)d_in[18];
  const float* bn2g   = (const float*)d_in[19];
  const float* bn2b   = (const float*)d_in[20];
  const float* dpw_w  = (const float*)d_in[21];
  const float* dbng   = (const float*)d_in[22];
  const float* dbnb   = (const float*)d_in[23];
  const float* gng    = (const float*)d_in[24];
  const float* gnb    = (const float*)d_in[25];
  float* out = (float*)d_out;

  float* ws = (float*)d_ws;
  bf16*  resT = (bf16*)ws;                       // 33,554,432 bf16 (pixel-major)
  bf16*  zT   = (bf16*)(ws + 16777216);          // 33,554,432 bf16 (pixel-major)
  float* zone = ws + 33554432;
  float* xz   = zone;                            // 4,194,304
  float* xc   = xz  + 4194304;                   // 2,097,152
  float* dbl  = xc  + 2097152;                   //   196,608
  float* dtb  = dbl + 196608;                    // 2,097,152
  bf16*  ybb  = (bf16*)(dtb + 2097152);          // 2,097,152 bf16 (1,048,576 f)
  float* t1   = zone;                            // overlay (8,388,608; ybb @8,585,216 safe)
  float* mo   = zone + 9633792;                  // 1,048,576
  float* resm = mo   + 1048576;                  //   262,144
  float* resn = resm + 262144;                   //   262,144
  float* pmax = resn + 262144;                   //   262,144
  float* pmin = pmax + 262144;                   //   262,144
  float* PT   = pmin + 262144;                   //   131,072
  bf16*  ubmax= (bf16*)(PT + 131072);            //   262,144 bf16 (131,072 f)
  bf16*  ubmin= (bf16*)(PT + 131072 + 131072);   //   262,144 bf16
  bf16*  Winb = (bf16*)(PT + 131072 + 262144);   //   524,288 bf16 (262,144 f)
  bf16*  Woutb= (bf16*)(PT + 131072 + 524288);   //   262,144 bf16 (131,072 f)
  bf16*  Wub  = (bf16*)(PT + 131072 + 655360);   //    65,536 bf16
  bf16*  Wdb  = (bf16*)(PT + 131072 + 688128);   //    65,536 bf16
  float* stat = PT + 131072 + 720896;            //     2,048
  float* statm1 = stat;        float* statr1 = stat + 256;
  float* statm2 = stat + 512;  float* statr2 = stat + 768;
  float* statm3 = stat + 1024; float* statr3 = stat + 1280;
  float* gsum   = stat + 1536; float* gssq   = stat + 1792;

  // weight prep
  transpose_k<<<(256*512+255)/256, 256,0,stream>>>(proj_w, PT, 1, 256, 512);
  wcvt<<<2048,256,0,stream>>>(in_w,  Winb, 524288);
  wcvt<<<1024,256,0,stream>>>(out_w, Woutb, 262144);
  wcvt<<<256,256,0,stream>>>(pw_w,  Wub, 65536);
  wcvt<<<256,256,0,stream>>>(dpw_w, Wdb, 65536);

  // reductions + pos-emb + LN -> result_max / result_min (b,128,256)
  r1_reduce_pe<<<2048,64,0,stream>>>(x, pos, pmax, pmin);
  ln_rows<<<1024,256,0,stream>>>(pmax, ln_g, ln_b, ubmax);
  ln_rows<<<1024,256,0,stream>>>(pmin, ln_g, ln_b, ubmin);

  // mamba (4 runs batched)
  m1_mfma<<<256,256,0,stream>>>(ubmax, ubmin, Winb, xz);
  m2_conv<<<8192,256,0,stream>>>(xz, conv_w, conv_b, xc);
  m3_xproj<<<4096,64,0,stream>>>(xc, xproj, dbl);
  m4_dt<<<8192,256,0,stream>>>(dbl, dt_w, dt_b, dtb);
  m5_scan<<<64,256,0,stream>>>(dtb, xc, dbl, xz, A_log, Dp, ybb);
  m6_mfma<<<64,256,0,stream>>>(ybb, Woutb, mo);
  ln_rows<<<4096,256,0,stream>>>(mo, ln_g, ln_b, nullptr);
  m7_proj<<<128,256,0,stream>>>(mo, PT, proj_b, resm, resn);
  ln_rows<<<1024,256,0,stream>>>(resm, ln_g, ln_b, nullptr);
  ln_rows<<<1024,256,0,stream>>>(resn, ln_g, ln_b, nullptr);

  // upsample branch (pixel-major) + MFMA pointwise + gate
  k1_deconv_T<<<8192,256,0,stream>>>(x, dw_w, bn1g, bn1b, zT);
  k2_mfma<<<dim3(256,8),256,0,stream>>>(zT, Wub, bn2g, bn2b, resm, resn, resT);

  // gn1 stats (pixel-major) -> MFMA downsample pointwise + BN
  gn_zero<<<2,256,0,stream>>>(gsum, 512);
  gn_stats_pm<<<dim3(64,8),256,0,stream>>>(resT, gsum, gssq);
  gn_fin<<<1,256,0,stream>>>(gsum, gssq, statm1, statr1);
  k4_mfma<<<dim3(64,8),256,0,stream>>>(resT, Wdb, statm1, statr1,
                                       gng, gnb, dbng, dbnb, t1);

  // gn2+add x -> gn3 -> out
  gn_stats<<<256,256,0,stream>>>(t1, 4096, statm2, statr2);
  k6_gn_add<<<32768,256,0,stream>>>(t1, x, statm2, statr2, gng, gnb);
  gn_stats<<<256,256,0,stream>>>(t1, 4096, statm3, statr3);
  k8_gn_out<<<32768,256,0,stream>>>(t1, statm3, statr3, gng, gnb, out);
}

// Round 6
// 599.723 us; speedup vs baseline: 3.2859x; 1.0660x over previous
//
#include <hip/hip_runtime.h>
#include <hip/hip_bf16.h>
#include <math.h>

typedef __hip_bfloat16 bf16;
typedef __attribute__((ext_vector_type(8))) short short8_t;
typedef __attribute__((ext_vector_type(4))) short short4_t;
typedef __attribute__((ext_vector_type(4))) float f32x4_t;

#define EPSV 1e-5f
#define BNSC 0.99999500003749968f  // 1/sqrt(1+1e-5)

__device__ __forceinline__ float bf2f(bf16 v){ return __bfloat162float(v); }
__device__ __forceinline__ bf16 f2bf(float v){ return __float2bfloat16(v); }

__device__ __forceinline__ float blk_sum(float v, float* sm){
  int tid = threadIdx.x;
  #pragma unroll
  for(int o=32;o>0;o>>=1) v += __shfl_down(v, o, 64);
  if((tid&63)==0) sm[tid>>6] = v;
  __syncthreads();
  float s = 0.f;
  int nw = blockDim.x>>6;
  for(int i=0;i<nw;i++) s += sm[i];
  __syncthreads();
  return s;
}

__device__ __forceinline__ float softplusf(float x){
  return (x > 20.f) ? x : __logf(1.f + __expf(x));
}
__device__ __forceinline__ float siluf(float x){
  return x / (1.f + __expf(-x));
}

// generic batched transpose: src (Bn,R,C) -> dst (Bn,C,R)
__global__ void transpose_k(const float* __restrict__ src, float* __restrict__ dst,
                            int Bn, int R, int C){
  int idx = blockIdx.x*256 + threadIdx.x;
  int rc = R*C;
  int total = Bn*rc;
  if(idx >= total) return;
  int d = idx / rc;
  int rem = idx - d*rc;
  int i = rem / C;
  int j = rem - i*C;
  dst[d*rc + j*R + i] = src[idx];
}

// f32 -> bf16 weight convert
__global__ void wcvt(const float* __restrict__ src, bf16* __restrict__ dst, int n){
  int i = blockIdx.x*256 + threadIdx.x;
  if(i < n) dst[i] = f2bf(src[i]);
}

// R1: per (b,c) slice: col max/min over h, row max/min over w, + pos-emb + idx
__global__ void r1_reduce_pe(const float* __restrict__ x, const float* __restrict__ pe,
                             float* __restrict__ pmax, float* __restrict__ pmin){
  __shared__ float tile[64*65];
  int bc = blockIdx.x;          // b*256 + c
  int b = bc >> 8, c = bc & 255;
  const float* xp = x + ((size_t)bc << 12);
  for(int i=threadIdx.x; i<4096; i+=64)
    tile[(i>>6)*65 + (i&63)] = xp[i];
  __syncthreads();
  int t = threadIdx.x;
  float cmx=-3.4e38f, cmn=3.4e38f; int cax=0, can=0;
  for(int h=0;h<64;h++){
    float v = tile[h*65 + t];
    if(v > cmx){ cmx=v; cax=h; }
    if(v < cmn){ cmn=v; can=h; }
  }
  float rmx=-3.4e38f, rmn=3.4e38f; int rax=0, ran=0;
  for(int w=0;w<64;w++){
    float v = tile[t*65 + w];
    if(v > rmx){ rmx=v; rax=w; }
    if(v < rmn){ rmn=v; ran=w; }
  }
  float coords = fmaxf((t + 0.5f)*0.25f - 0.5f, 0.f);
  int i0 = (int)floorf(coords);
  int i1 = min(i0+1, 15);
  float wg = coords - (float)i0;
  float pos = pe[c*16+i0]*(1.f-wg) + pe[c*16+i1]*wg;
  size_t base_col = ((size_t)b*128 + t)*256 + c;
  size_t base_row = ((size_t)b*128 + 64 + t)*256 + c;
  pmax[base_col] = cmx + pos + (float)cax;
  pmin[base_col] = cmn + pos + (float)can;
  pmax[base_row] = rmx + pos + (float)rax;
  pmin[base_row] = rmn + pos + (float)ran;
}

// row LayerNorm over 256, in place; optional bf16 copy out
__global__ void ln_rows(float* __restrict__ buf, const float* __restrict__ g,
                        const float* __restrict__ bb, bf16* __restrict__ bout){
  __shared__ float sm[8];
  int row = blockIdx.x, t = threadIdx.x;
  float v = buf[(size_t)row*256 + t];
  float m = blk_sum(v, sm) * (1.f/256.f);
  float dv = v - m;
  float var = blk_sum(dv*dv, sm) * (1.f/256.f);
  float r = dv * rsqrtf(var + EPSV) * g[t] + bb[t];
  buf[(size_t)row*256 + t] = r;
  if(bout) bout[(size_t)row*256 + t] = f2bf(r);
}

// M1 (MFMA): xz[rb][l][i] = sum_c u_bf(b,l_eff,c) * in_w_bf[d][i][c]
__global__ __launch_bounds__(256,2)
void m1_mfma(const bf16* __restrict__ ubmax, const bf16* __restrict__ ubmin,
             const bf16* __restrict__ Win, float* __restrict__ xz){
  __shared__ bf16 att[64*264];
  int bx = blockIdx.x;
  int it = bx & 3, lt = (bx>>2)&1, b = (bx>>3)&7, r = bx>>6;
  int d = r & 1;
  const bf16* u = (r < 2) ? ubmax : ubmin;
  int flip = r & 1;
  int t = threadIdx.x;
  {
    int pr = t>>5, cc = (t&31)*8;
    #pragma unroll
    for(int i=0;i<8;i++){
      int p = pr + i*8;
      int l = lt*64 + p;
      int le = flip ? (127 - l) : l;
      short8_t v = *(const short8_t*)((const short*)u + ((size_t)(b*128 + le))*256 + cc);
      *(short8_t*)&att[p*264 + cc] = v;
    }
  }
  __syncthreads();
  int wv = t>>6, lane = t&63, quad = lane>>4, l16 = lane&15;
  int m0 = wv*64;
  f32x4_t acc[4][4];
  #pragma unroll
  for(int ms=0;ms<4;ms++)
    #pragma unroll
    for(int ns=0;ns<4;ns++) acc[ms][ns] = (f32x4_t){0.f,0.f,0.f,0.f};
  const short* wbase = (const short*)Win + ((size_t)d*1024 + it*256)*256;
  for(int k0=0;k0<256;k0+=32){
    short8_t afr[4], bfr[4];
    #pragma unroll
    for(int ms=0;ms<4;ms++)
      afr[ms] = *(const short8_t*)(wbase + (size_t)(m0 + ms*16 + l16)*256 + k0 + quad*8);
    #pragma unroll
    for(int ns=0;ns<4;ns++)
      bfr[ns] = *(const short8_t*)&att[(ns*16 + l16)*264 + k0 + quad*8];
    #pragma unroll
    for(int ms=0;ms<4;ms++)
      #pragma unroll
      for(int ns=0;ns<4;ns++)
        acc[ms][ns] = __builtin_amdgcn_mfma_f32_16x16x32_bf16(afr[ms], bfr[ns], acc[ms][ns], 0,0,0);
  }
  int rb = r*8 + b;
  #pragma unroll
  for(int ns=0;ns<4;ns++){
    int l = lt*64 + ns*16 + l16;
    float* dst = xz + ((size_t)rb*128 + l)*1024 + it*256;
    #pragma unroll
    for(int ms=0;ms<4;ms++){
      int i = m0 + ms*16 + quad*4;
      *(f32x4_t*)(dst + i) = acc[ms][ns];
    }
  }
}

// M2: causal depthwise conv (k=4) + silu over xh part of xz
__global__ void m2_conv(const float* __restrict__ xz, const float* __restrict__ cw,
                        const float* __restrict__ cb, float* __restrict__ xc){
  int idx = blockIdx.x*256 + threadIdx.x;
  int dd = idx & 511;
  int l  = (idx >> 9) & 127;
  int rb = idx >> 16;
  int d = (rb >> 3) & 1;
  const float* base = xz + ((size_t)rb*128)*1024 + dd;
  float s = cb[d*512 + dd];
  const float* w = cw + (size_t)(d*512 + dd)*4;
  #pragma unroll
  for(int k=0;k<4;k++){
    int ls = l - 3 + k;
    if(ls >= 0) s += base[(size_t)ls*1024] * w[k];
  }
  xc[idx] = siluf(s);
}

// M3: dbl[row][e] = sum_dd xc[row][dd] * xproj[d][e][dd]
__global__ void m3_xproj(const float* __restrict__ xc, const float* __restrict__ xproj,
                         float* __restrict__ dbl){
  __shared__ float row[512];
  int rowid = blockIdx.x;
  int d = (rowid >> 10) & 1;
  for(int i=threadIdx.x;i<512;i+=64) row[i] = xc[(size_t)rowid*512 + i];
  __syncthreads();
  if(threadIdx.x < 48){
    const float* wp = xproj + (size_t)(d*48 + threadIdx.x)*512;
    float s = 0.f;
    for(int k=0;k<512;k++) s += row[k]*wp[k];
    dbl[(size_t)rowid*48 + threadIdx.x] = s;
  }
}

// M4: dt[row][dd] = softplus(sum_r dbl[row][r]*dt_w[d][dd][r] + dt_b[d][dd])
__global__ void m4_dt(const float* __restrict__ dbl, const float* __restrict__ dtw,
                      const float* __restrict__ dtbias, float* __restrict__ dt){
  int idx = blockIdx.x*256 + threadIdx.x;
  int dd = idx & 511;
  int rowid = idx >> 9;
  int d = (rowid >> 10) & 1;
  const float* dr = dbl + (size_t)rowid*48;
  const float* wp = dtw + (size_t)(d*512 + dd)*16;
  float s = dtbias[d*512 + dd];
  #pragma unroll
  for(int r=0;r<16;r++) s += dr[r]*wp[r];
  dt[idx] = softplusf(s);
}

// M5a: chunked scan pass A. grid 512: seg(3b)|half(1b)|rb(5b). 16 steps/segment.
// P[(rb*8+seg)*512+dd][16] = prod dA ; Hloc = local state from h=0
__global__ void m5_passA(const float* __restrict__ dt, const float* __restrict__ xc,
                         const float* __restrict__ dbl, const float* __restrict__ Alog,
                         float* __restrict__ P, float* __restrict__ Hl){
  int bx = blockIdx.x;
  int seg = bx & 7, half = (bx>>3)&1, rb = bx>>4;
  int dd = half*256 + threadIdx.x;
  int d = (rb>>3)&1;
  float A[16], h[16], pr[16];
  #pragma unroll
  for(int s=0;s<16;s++){
    A[s] = -__expf(Alog[(size_t)(d*512 + dd)*16 + s]);
    h[s] = 0.f; pr[s] = 1.f;
  }
  int l0 = seg*16;
  for(int l=l0;l<l0+16;l++){
    size_t row = (size_t)rb*128 + l;
    float dtv = dt[row*512 + dd];
    float xcv = xc[row*512 + dd];
    float bx_ = dtv*xcv;
    const float* dr = dbl + row*48;
    #pragma unroll
    for(int s=0;s<16;s++){
      float dA = __expf(dtv*A[s]);
      pr[s] *= dA;
      h[s] = dA*h[s] + bx_*dr[16+s];
    }
  }
  size_t o = ((size_t)(rb*8 + seg)*512 + dd)*16;
  #pragma unroll
  for(int s=0;s<16;s+=4){
    *(f32x4_t*)(P  + o + s) = (f32x4_t){pr[s],pr[s+1],pr[s+2],pr[s+3]};
    *(f32x4_t*)(Hl + o + s) = (f32x4_t){h[s],h[s+1],h[s+2],h[s+3]};
  }
}

// M5b: pass B — combine prefix (P,H), re-scan segment, emit y -> ybb (bf16)
__global__ void m5_passB(const float* __restrict__ dt, const float* __restrict__ xc,
                         const float* __restrict__ dbl, const float* __restrict__ xz,
                         const float* __restrict__ Alog, const float* __restrict__ Dp,
                         const float* __restrict__ P, const float* __restrict__ Hl,
                         bf16* __restrict__ ybb){
  int bx = blockIdx.x;
  int seg = bx & 7, half = (bx>>3)&1, rb = bx>>4;
  int dd = half*256 + threadIdx.x;
  int d = (rb>>3)&1;
  float A[16], h[16];
  #pragma unroll
  for(int s=0;s<16;s++){
    A[s] = -__expf(Alog[(size_t)(d*512 + dd)*16 + s]);
    h[s] = 0.f;
  }
  // prefix combine
  for(int j=0;j<seg;j++){
    size_t o = ((size_t)(rb*8 + j)*512 + dd)*16;
    #pragma unroll
    for(int s=0;s<16;s+=4){
      f32x4_t pv = *(const f32x4_t*)(P + o + s);
      f32x4_t hv = *(const f32x4_t*)(Hl + o + s);
      h[s]   = pv[0]*h[s]   + hv[0];
      h[s+1] = pv[1]*h[s+1] + hv[1];
      h[s+2] = pv[2]*h[s+2] + hv[2];
      h[s+3] = pv[3]*h[s+3] + hv[3];
    }
  }
  float Dv = Dp[d*512 + dd];
  int l0 = seg*16;
  for(int l=l0;l<l0+16;l++){
    size_t row = (size_t)rb*128 + l;
    float dtv = dt[row*512 + dd];
    float xcv = xc[row*512 + dd];
    float zgv = xz[row*1024 + 512 + dd];
    const float* dr = dbl + row*48;
    float bx_ = dtv*xcv;
    float y = 0.f;
    #pragma unroll
    for(int s=0;s<16;s++){
      h[s] = __expf(dtv*A[s])*h[s] + bx_*dr[16+s];
      y += h[s]*dr[32+s];
    }
    ybb[row*512 + dd] = f2bf((y + xcv*Dv) * siluf(zgv));
  }
}

// M6 (MFMA): mo[row][o] = sum_dd yb_bf[row][dd] * out_w_bf[d][o][dd]
__global__ __launch_bounds__(256,2)
void m6_mfma(const bf16* __restrict__ ybb, const bf16* __restrict__ Wout,
             float* __restrict__ mo){
  __shared__ bf16 ybt[64*520];
  int bx = blockIdx.x;
  int lt = bx & 1, b = (bx>>1)&7, r = bx>>4;
  int d = r & 1, rb = r*8 + b;
  size_t rowbase = (size_t)rb*128 + lt*64;
  int t = threadIdx.x;
  for(int i=t;i<4096;i+=256){
    int row = i>>6, c8 = (i&63)*8;
    short8_t v = *(const short8_t*)((const short*)ybb + (rowbase + row)*512 + c8);
    *(short8_t*)&ybt[row*520 + c8] = v;
  }
  __syncthreads();
  int wv = t>>6, lane = t&63, quad = lane>>4, l16 = lane&15;
  int m0 = wv*64;
  f32x4_t acc[4][4];
  #pragma unroll
  for(int ms=0;ms<4;ms++)
    #pragma unroll
    for(int ns=0;ns<4;ns++) acc[ms][ns] = (f32x4_t){0.f,0.f,0.f,0.f};
  const short* wbase = (const short*)Wout + (size_t)d*256*512;
  for(int k0=0;k0<512;k0+=32){
    short8_t afr[4], bfr[4];
    #pragma unroll
    for(int ms=0;ms<4;ms++)
      afr[ms] = *(const short8_t*)(wbase + (size_t)(m0 + ms*16 + l16)*512 + k0 + quad*8);
    #pragma unroll
    for(int ns=0;ns<4;ns++)
      bfr[ns] = *(const short8_t*)&ybt[(ns*16 + l16)*520 + k0 + quad*8];
    #pragma unroll
    for(int ms=0;ms<4;ms++)
      #pragma unroll
      for(int ns=0;ns<4;ns++)
        acc[ms][ns] = __builtin_amdgcn_mfma_f32_16x16x32_bf16(afr[ms], bfr[ns], acc[ms][ns], 0,0,0);
  }
  #pragma unroll
  for(int ns=0;ns<4;ns++){
    int l = ns*16 + l16;
    float* dst = mo + (rowbase + l)*256;
    #pragma unroll
    for(int ms=0;ms<4;ms++){
      int o = m0 + ms*16 + quad*4;
      *(f32x4_t*)(dst + o) = acc[ms][ns];
    }
  }
}

// M7
__global__ void m7_proj(const float* __restrict__ mo, const float* __restrict__ PT,
                        const float* __restrict__ pb, float* __restrict__ resm,
                        float* __restrict__ resn){
  __shared__ float ct[16*512];
  int bx = blockIdx.x;
  int t = bx >> 6, rem = bx & 63, b = rem >> 3, lt = rem & 7;
  int fr = t*2, br = t*2 + 1;
  for(int i=threadIdx.x;i<16*512;i+=256){
    int lr = i >> 9, k = i & 511;
    int l = lt*16 + lr;
    ct[i] = (k < 256)
      ? mo[(((size_t)(fr*8+b)*128) + l)*256 + k]
      : mo[(((size_t)(br*8+b)*128) + (127-l))*256 + (k-256)];
  }
  __syncthreads();
  float acc[16];
  #pragma unroll
  for(int q=0;q<16;q++) acc[q] = 0.f;
  for(int k=0;k<512;k++){
    float pv = PT[(size_t)k*256 + threadIdx.x];
    #pragma unroll
    for(int q=0;q<16;q++) acc[q] += pv * ct[(q<<9) + k];
  }
  float* dst = t ? resn : resm;
  float bias = pb[threadIdx.x];
  #pragma unroll
  for(int q=0;q<16;q++)
    dst[((size_t)b*128 + lt*16 + q)*256 + threadIdx.x] = acc[q] + bias;
}

// K1: stride-2 transposed depthwise 3x3 + BN + ReLU -> zT (pixel-major bf16)
__global__ __launch_bounds__(256)
void k1_deconv_T(const float* __restrict__ x, const float* __restrict__ wdw,
                 const float* __restrict__ g1, const float* __restrict__ b1,
                 bf16* __restrict__ zT){
  __shared__ float in[2*64*33];
  __shared__ bf16 ot[64*80];
  int bx = blockIdx.x;
  int cb = bx & 3, half = (bx>>2)&1, h = (bx>>3)&127, b = bx>>10;
  int c0 = cb*64, w0 = half*64, iw0 = w0>>1;
  int h_odd = h & 1;
  int ihA = h_odd ? (h-1)>>1 : h>>1;
  int ihB = (h+1)>>1;
  bool hasB = h_odd && (ihB < 64);
  for(int i = threadIdx.x; i < 4224; i += 256){
    int row = i / 2112;
    int rem = i - row*2112;
    int c = rem / 33;
    int iw = rem - c*33;
    int ihl = row ? ihB : ihA;
    bool valid = (iw0 + iw < 64) && (row == 0 || hasB);
    in[i] = valid ? x[(((size_t)b*256 + c0 + c)<<12) + (ihl<<6) + iw0 + iw] : 0.f;
  }
  __syncthreads();
  int c = threadIdx.x & 63, g = threadIdx.x >> 6;
  const float* wp = wdw + (c0+c)*9;
  int khA3 = h_odd ? 6 : 3;
  float wA0 = wp[khA3], wA1 = wp[khA3+1], wA2 = wp[khA3+2];
  float wB0 = wp[0],    wB1 = wp[1],      wB2 = wp[2];
  float scale = g1[c0+c]*BNSC, bias = b1[c0+c];
  const float* inA = in + c*33;
  const float* inB = in + 2112 + c*33;
  #pragma unroll
  for(int i=0;i<16;i++){
    int wi = g*16 + i;
    float s;
    if(!(i&1)){
      int iw = wi>>1;
      s = inA[iw]*wA1 + inB[iw]*wB1;
    } else {
      int iwa = (wi-1)>>1, iwb = (wi+1)>>1;
      s = inA[iwa]*wA2 + inA[iwb]*wA0 + inB[iwa]*wB2 + inB[iwb]*wB0;
    }
    ot[wi*80 + c] = f2bf(fmaxf(s*scale + bias, 0.f));
  }
  __syncthreads();
  int rr = threadIdx.x >> 3;
  int co = (threadIdx.x & 7) * 8;
  size_t obase = (((size_t)b*16384) + (size_t)h*128 + w0)*256 + c0;
  #pragma unroll
  for(int pass=0; pass<2; pass++){
    int wi = rr + pass*32;
    short8_t v = *(const short8_t*)&ot[wi*80 + co];
    *(short8_t*)((short*)zT + obase + (size_t)wi*256 + co) = v;
  }
}

// K2 (MFMA): 128 pixels x 256 outputs, K=256, prefetched weights
__global__ __launch_bounds__(256,2)
void k2_mfma(const bf16* __restrict__ zT, const bf16* __restrict__ Wub,
             const float* __restrict__ g2, const float* __restrict__ b2,
             const float* __restrict__ resm, const float* __restrict__ resn,
             bf16* __restrict__ resT){
  __shared__ bf16 zt[128*264];
  int b = blockIdx.y;
  int p0 = blockIdx.x*128;
  int t = threadIdx.x;
  {
    const short* src = (const short*)zT + (((size_t)b*16384 + p0)*256);
    int pr = t>>5;
    int cc = (t&31)*8;
    #pragma unroll
    for(int i=0;i<16;i++){
      int p = pr + i*8;
      short8_t v = *(const short8_t*)(src + (size_t)p*256 + cc);
      *(short8_t*)&zt[p*264 + cc] = v;
    }
  }
  __syncthreads();
  int wv = t>>6, lane = t&63, quad = lane>>4, l16 = lane&15;
  int m0 = wv*64;
  f32x4_t acc[4][8];
  #pragma unroll
  for(int ms=0;ms<4;ms++)
    #pragma unroll
    for(int ns=0;ns<8;ns++) acc[ms][ns] = (f32x4_t){0.f,0.f,0.f,0.f};
  const short* wp = (const short*)Wub + (size_t)(m0 + l16)*256 + quad*8;
  short8_t afr[4];
  #pragma unroll
  for(int ms=0;ms<4;ms++) afr[ms] = *(const short8_t*)(wp + (size_t)ms*16*256);
  for(int k0=0;k0<256;k0+=32){
    short8_t anext[4];
    if(k0 + 32 < 256){
      #pragma unroll
      for(int ms=0;ms<4;ms++)
        anext[ms] = *(const short8_t*)(wp + (size_t)ms*16*256 + k0 + 32);
    }
    short8_t bfr[8];
    #pragma unroll
    for(int ns=0;ns<8;ns++)
      bfr[ns] = *(const short8_t*)&zt[(ns*16 + l16)*264 + k0 + quad*8];
    #pragma unroll
    for(int ms=0;ms<4;ms++)
      #pragma unroll
      for(int ns=0;ns<8;ns++)
        acc[ms][ns] = __builtin_amdgcn_mfma_f32_16x16x32_bf16(afr[ms], bfr[ns], acc[ms][ns], 0,0,0);
    #pragma unroll
    for(int ms=0;ms<4;ms++) afr[ms] = anext[ms];
  }
  #pragma unroll
  for(int ns=0;ns<8;ns++){
    int p = p0 + ns*16 + l16;
    int hh = p>>7, ww = p&127;
    const float* rm = resm + ((size_t)b*128+hh)*256;
    const float* rn = resn + ((size_t)b*128+ww)*256;
    size_t orow = ((size_t)b*16384 + p)*256;
    #pragma unroll
    for(int ms=0;ms<4;ms++){
      int o = m0 + ms*16 + quad*4;
      f32x4_t a = acc[ms][ns];
      f32x4_t gv = *(const f32x4_t*)(g2+o);
      f32x4_t bv = *(const f32x4_t*)(b2+o);
      f32x4_t rmv = *(const f32x4_t*)(rm+o);
      f32x4_t rnv = *(const f32x4_t*)(rn+o);
      alignas(8) bf16 ov[4];
      #pragma unroll
      for(int r=0;r<4;r++){
        float zv = a[r]*(gv[r]*BNSC) + bv[r];
        zv = fminf(fmaxf(zv, 0.f), 6.f);
        float gate = fminf(fmaxf(rmv[r]+rnv[r]+3.f, 0.f), 6.f)*(1.f/6.f);
        ov[r] = f2bf(zv*gate);
      }
      *(short4_t*)((short*)resT + orow + o) = *(const short4_t*)ov;
    }
  }
}

// zero the gn1 accumulators
__global__ void gn_zero(float* __restrict__ p, int n){
  int i = blockIdx.x*256 + threadIdx.x;
  if(i<n) p[i] = 0.f;
}

// GN1 stats over pixel-major resT
__global__ void gn_stats_pm(const bf16* __restrict__ resT, float* __restrict__ sum,
                            float* __restrict__ ssq){
  __shared__ float ls[256], lq[256];
  int b = blockIdx.y, p0 = blockIdx.x*256;
  int c = threadIdx.x;
  const short* src = (const short*)resT + ((size_t)b*16384 + p0)*256 + c;
  float s=0.f, q=0.f;
  for(int i=0;i<256;i++){
    bf16 raw; *(short*)&raw = src[(size_t)i*256];
    float v = bf2f(raw);
    s += v; q += v*v;
  }
  ls[c]=s; lq[c]=q;
  __syncthreads();
  if(c<32){
    float S=0.f,Q=0.f;
    #pragma unroll
    for(int j=0;j<8;j++){ S+=ls[c*8+j]; Q+=lq[c*8+j]; }
    atomicAdd(&sum[b*32+c], S);
    atomicAdd(&ssq[b*32+c], Q);
  }
}

__global__ void gn_fin(const float* __restrict__ sum, const float* __restrict__ ssq,
                       float* __restrict__ statm, float* __restrict__ statr){
  int i = threadIdx.x;
  float m = sum[i] * (1.f/131072.f);
  float var = ssq[i] * (1.f/131072.f) - m*m;
  statm[i] = m;
  statr[i] = rsqrtf(var + EPSV);
}

// K4 (MFMA): t1[b][o][p'] = BN(sum_c Wd[o][c] * gn1(resT[b][2y,2x][c]))
__global__ __launch_bounds__(256,2)
void k4_mfma(const bf16* __restrict__ resT, const bf16* __restrict__ Wdb,
             const float* __restrict__ statm, const float* __restrict__ statr,
             const float* __restrict__ gng, const float* __restrict__ gnb,
             const float* __restrict__ dbg, const float* __restrict__ dbb,
             float* __restrict__ t1){
  __shared__ bf16 at[64*264];
  __shared__ float sc[256], sb[256];
  int b = blockIdx.y;
  int q0 = blockIdx.x*64;
  int t = threadIdx.x;
  {
    int cch = t, g = cch>>3;
    float m = statm[b*32+g], rs = statr[b*32+g];
    float s = rs*gng[cch];
    sc[cch] = s; sb[cch] = gnb[cch] - m*s;
  }
  __syncthreads();
  {
    int pr = t>>5;
    int cc = (t&31)*8;
    #pragma unroll
    for(int i=0;i<8;i++){
      int q = pr + i*8;
      int qq = q0 + q;
      int y = qq>>6, xw = qq&63;
      size_t srow = ((size_t)b*16384 + (size_t)y*256 + xw*2)*256;
      short8_t v = *(const short8_t*)((const short*)resT + srow + cc);
      const bf16* vv = (const bf16*)&v;
      alignas(16) bf16 ov[8];
      #pragma unroll
      for(int j=0;j<8;j++) ov[j] = f2bf(bf2f(vv[j])*sc[cc+j] + sb[cc+j]);
      *(short8_t*)&at[q*264 + cc] = *(const short8_t*)ov;
    }
  }
  __syncthreads();
  int wv = t>>6, lane = t&63, quad = lane>>4, l16 = lane&15;
  int n0 = wv*64;
  f32x4_t acc[4][4];
  #pragma unroll
  for(int ms=0;ms<4;ms++)
    #pragma unroll
    for(int ns=0;ns<4;ns++) acc[ms][ns] = (f32x4_t){0.f,0.f,0.f,0.f};
  for(int k0=0;k0<256;k0+=32){
    short8_t afr[4], bfr[4];
    #pragma unroll
    for(int ms=0;ms<4;ms++) afr[ms] = *(const short8_t*)&at[(ms*16 + l16)*264 + k0 + quad*8];
    const short* wp = (const short*)Wdb + (size_t)(n0 + l16)*256 + k0 + quad*8;
    #pragma unroll
    for(int ns=0;ns<4;ns++) bfr[ns] = *(const short8_t*)(wp + (size_t)ns*16*256);
    #pragma unroll
    for(int ms=0;ms<4;ms++)
      #pragma unroll
      for(int ns=0;ns<4;ns++)
        acc[ms][ns] = __builtin_amdgcn_mfma_f32_16x16x32_bf16(afr[ms], bfr[ns], acc[ms][ns], 0,0,0);
  }
  #pragma unroll
  for(int ns=0;ns<4;ns++){
    int o = n0 + ns*16 + l16;
    float s2 = dbg[o]*BNSC, bb2 = dbb[o];
    float* dst = t1 + (((size_t)b*256 + o) << 12);
    #pragma unroll
    for(int ms=0;ms<4;ms++){
      int ps = q0 + ms*16 + quad*4;
      f32x4_t a = acc[ms][ns];
      f32x4_t ov;
      #pragma unroll
      for(int r=0;r<4;r++) ov[r] = a[r]*s2 + bb2;
      *(f32x4_t*)(dst + ps) = ov;
    }
  }
}

// GN stats over channel-major f32 (t1)
__global__ void gn_stats(const float* __restrict__ src, int HW,
                         float* __restrict__ statm, float* __restrict__ statr){
  __shared__ float sm[8];
  int bg = blockIdx.x;
  int b = bg >> 5, g = bg & 31;
  size_t base = ((size_t)(b*256 + g*8))*(size_t)HW;
  int n = 8*HW;
  const float* p = src + base;
  float s = 0.f, ss = 0.f;
  for(int i=threadIdx.x;i<n;i+=256){ float v = p[i]; s += v; ss += v*v; }
  s = blk_sum(s, sm);
  ss = blk_sum(ss, sm);
  if(threadIdx.x == 0){
    float m = s/(float)n;
    float var = ss/(float)n - m*m;
    statm[bg] = m;
    statr[bg] = rsqrtf(var + EPSV);
  }
}

// K6: t1 = gn2(t1) + x
__global__ void k6_gn_add(float* __restrict__ t1, const float* __restrict__ x,
                          const float* __restrict__ statm, const float* __restrict__ statr,
                          const float* __restrict__ gng, const float* __restrict__ gnb){
  int idx = blockIdx.x*256 + threadIdx.x;
  int c = (idx >> 12) & 255, b = idx >> 20, g = c >> 3;
  float m = statm[b*32 + g], rs = statr[b*32 + g];
  t1[idx] = (t1[idx] - m)*rs*gng[c] + gnb[c] + x[idx];
}

// K8: out = gn3(t1)
__global__ void k8_gn_out(const float* __restrict__ t1, const float* __restrict__ statm,
                          const float* __restrict__ statr, const float* __restrict__ gng,
                          const float* __restrict__ gnb, float* __restrict__ out){
  int idx = blockIdx.x*256 + threadIdx.x;
  int c = (idx >> 12) & 255, b = idx >> 20, g = c >> 3;
  float m = statm[b*32 + g], rs = statr[b*32 + g];
  out[idx] = (t1[idx] - m)*rs*gng[c] + gnb[c];
}

extern "C" void kernel_launch(void* const* d_in, const int* in_sizes, int n_in,
                              void* d_out, int out_size, void* d_ws, size_t ws_size,
                              hipStream_t stream){
  const float* x      = (const float*)d_in[0];
  const float* pos    = (const float*)d_in[1];
  const float* ln_g   = (const float*)d_in[2];
  const float* ln_b   = (const float*)d_in[3];
  const float* in_w   = (const float*)d_in[4];
  const float* conv_w = (const float*)d_in[5];
  const float* conv_b = (const float*)d_in[6];
  const float* xproj  = (const float*)d_in[7];
  const float* dt_w   = (const float*)d_in[8];
  const float* dt_b   = (const float*)d_in[9];
  const float* A_log  = (const float*)d_in[10];
  const float* Dp     = (const float*)d_in[11];
  const float* out_w  = (const float*)d_in[12];
  const float* proj_w = (const float*)d_in[13];
  const float* proj_b = (const float*)d_in[14];
  const float* dw_w   = (const float*)d_in[15];
  const float* bn1g   = (const float*)d_in[16];
  const float* bn1b   = (const float*)d_in[17];
  const float* pw_w   = (const float*)d_in[18];
  const float* bn2g   = (const float*)d_in[19];
  const float* bn2b   = (const float*)d_in[20];
  const float* dpw_w  = (const float*)d_in[21];
  const float* dbng   = (const float*)d_in[22];
  const float* dbnb   = (const float*)d_in[23];
  const float* gng    = (const float*)d_in[24];
  const float* gnb    = (const float*)d_in[25];
  float* out = (float*)d_out;

  float* ws = (float*)d_ws;
  bf16*  resT = (bf16*)ws;                       // pixel-major (b,p,c)
  bf16*  zT   = (bf16*)(ws + 16777216);          // pixel-major (b,p,c)
  // scan P/H overlay zT region (zT written later by k1)
  float* scanP = ws + 16777216;                  // 2,097,152
  float* scanH = ws + 16777216 + 2097152;        // 2,097,152
  float* zone = ws + 33554432;
  float* xz   = zone;                            // 4,194,304
  float* xc   = xz  + 4194304;                   // 2,097,152
  float* dbl  = xc  + 2097152;                   //   196,608
  float* dtb  = dbl + 196608;                    // 2,097,152
  bf16*  ybb  = (bf16*)(dtb + 2097152);          // 1,048,576 f worth
  float* t1   = zone;                            // overlay (first 8,388,608)
  float* mo   = zone + 9633792;                  // 1,048,576
  float* resm = mo   + 1048576;                  //   262,144
  float* resn = resm + 262144;                   //   262,144
  float* pmax = resn + 262144;                   //   262,144
  float* pmin = pmax + 262144;                   //   262,144
  float* PT   = pmin + 262144;                   //   131,072
  bf16*  ubmax= (bf16*)(PT + 131072);
  bf16*  ubmin= (bf16*)(PT + 131072 + 131072);
  bf16*  Winb = (bf16*)(PT + 131072 + 262144);
  bf16*  Woutb= (bf16*)(PT + 131072 + 524288);
  bf16*  Wub  = (bf16*)(PT + 131072 + 655360);
  bf16*  Wdb  = (bf16*)(PT + 131072 + 688128);
  float* stat = PT + 131072 + 720896;
  float* statm1 = stat;        float* statr1 = stat + 256;
  float* statm2 = stat + 512;  float* statr2 = stat + 768;
  float* statm3 = stat + 1024; float* statr3 = stat + 1280;
  float* gsum   = stat + 1536; float* gssq   = stat + 1792;

  // weight prep
  transpose_k<<<(256*512+255)/256, 256,0,stream>>>(proj_w, PT, 1, 256, 512);
  wcvt<<<2048,256,0,stream>>>(in_w,  Winb, 524288);
  wcvt<<<1024,256,0,stream>>>(out_w, Woutb, 262144);
  wcvt<<<256,256,0,stream>>>(pw_w,  Wub, 65536);
  wcvt<<<256,256,0,stream>>>(dpw_w, Wdb, 65536);

  // reductions + pos-emb + LN
  r1_reduce_pe<<<2048,64,0,stream>>>(x, pos, pmax, pmin);
  ln_rows<<<1024,256,0,stream>>>(pmax, ln_g, ln_b, ubmax);
  ln_rows<<<1024,256,0,stream>>>(pmin, ln_g, ln_b, ubmin);

  // mamba (4 runs batched)
  m1_mfma<<<256,256,0,stream>>>(ubmax, ubmin, Winb, xz);
  m2_conv<<<8192,256,0,stream>>>(xz, conv_w, conv_b, xc);
  m3_xproj<<<4096,64,0,stream>>>(xc, xproj, dbl);
  m4_dt<<<8192,256,0,stream>>>(dbl, dt_w, dt_b, dtb);
  m5_passA<<<512,256,0,stream>>>(dtb, xc, dbl, A_log, scanP, scanH);
  m5_passB<<<512,256,0,stream>>>(dtb, xc, dbl, xz, A_log, Dp, scanP, scanH, ybb);
  m6_mfma<<<64,256,0,stream>>>(ybb, Woutb, mo);
  ln_rows<<<4096,256,0,stream>>>(mo, ln_g, ln_b, nullptr);
  m7_proj<<<128,256,0,stream>>>(mo, PT, proj_b, resm, resn);
  ln_rows<<<1024,256,0,stream>>>(resm, ln_g, ln_b, nullptr);
  ln_rows<<<1024,256,0,stream>>>(resn, ln_g, ln_b, nullptr);

  // upsample branch (pixel-major) + MFMA pointwise + gate
  k1_deconv_T<<<8192,256,0,stream>>>(x, dw_w, bn1g, bn1b, zT);
  k2_mfma<<<dim3(128,8),256,0,stream>>>(zT, Wub, bn2g, bn2b, resm, resn, resT);

  // gn1 -> downsample pointwise + BN
  gn_zero<<<2,256,0,stream>>>(gsum, 512);
  gn_stats_pm<<<dim3(64,8),256,0,stream>>>(resT, gsum, gssq);
  gn_fin<<<1,256,0,stream>>>(gsum, gssq, statm1, statr1);
  k4_mfma<<<dim3(64,8),256,0,stream>>>(resT, Wdb, statm1, statr1,
                                       gng, gnb, dbng, dbnb, t1);

  // gn2+add x -> gn3 -> out
  gn_stats<<<256,256,0,stream>>>(t1, 4096, statm2, statr2);
  k6_gn_add<<<32768,256,0,stream>>>(t1, x, statm2, statr2, gng, gnb);
  gn_stats<<<256,256,0,stream>>>(t1, 4096, statm3, statr3);
  k8_gn_out<<<32768,256,0,stream>>>(t1, statm3, statr3, gng, gnb, out);
}